// Round 1
// baseline (3470.020 us; speedup 1.0000x reference)
//
#include <hip/hip_runtime.h>
#include <hip/hip_bf16.h>
#include <math.h>

#define L_SEQ 2048
#define B_SZ 2
#define D_MODEL 768
#define D_INNER 1536
#define D_STATE 16
#define DT_RANK 48

static __device__ __forceinline__ float siluf(float v) {
  return v / (1.0f + __expf(-v));
}
static __device__ __forceinline__ float softplusf(float v) {
  return fmaxf(v, 0.0f) + log1pf(__expf(-fabsf(v)));
}

// C = A @ W^T with optional epilogues.
// A: [M][lda] fp32, W: [N][K] fp32 row-major.
// MODE 0: C0[row*ldc+n] = acc
// MODE 1: split xz -> n<D_INNER to C0 (x), else C1 (z), both ld=D_INNER
// MODE 2: softplus(acc + bias[n]) -> C0
// MODE 3: C0[row*ldc+n] += acc
// REV_A / REV_C: map row (b,t) -> (b, L-1-t) on the A-read / C-write side.
template<int MODE, int REV_A, int REV_C>
__global__ __launch_bounds__(256) void gemm_nt(
    const float* __restrict__ A, int lda,
    const float* __restrict__ W,
    const float* __restrict__ bias,
    float* __restrict__ C0, float* __restrict__ C1, int ldc,
    int M, int N, int K)
{
  __shared__ float As[16][65];
  __shared__ float Ws[16][65];
  const int tid = threadIdx.x;
  const int m0 = blockIdx.y * 64, n0 = blockIdx.x * 64;
  const int tx = tid & 15, ty = tid >> 4;
  const int lk = tid & 15, lr = tid >> 4;
  float acc[4][4] = {};
  for (int k0 = 0; k0 < K; k0 += 16) {
    #pragma unroll
    for (int i = 0; i < 4; ++i) {
      int m = lr + 16 * i;
      int mr = m0 + m;
      float v = 0.f;
      if (mr < M) {
        int row = mr;
        if (REV_A) { int b = mr >> 11, t = mr & (L_SEQ - 1); row = (b << 11) | (L_SEQ - 1 - t); }
        v = A[(long)row * lda + k0 + lk];
      }
      As[lk][m] = v;
    }
    #pragma unroll
    for (int i = 0; i < 4; ++i) {
      int n = lr + 16 * i;
      int nr = n0 + n;
      float v = 0.f;
      if (nr < N) v = W[(long)nr * K + k0 + lk];
      Ws[lk][n] = v;
    }
    __syncthreads();
    #pragma unroll
    for (int kk = 0; kk < 16; ++kk) {
      float a[4], bb[4];
      #pragma unroll
      for (int i = 0; i < 4; ++i) a[i] = As[kk][ty + 16 * i];
      #pragma unroll
      for (int j = 0; j < 4; ++j) bb[j] = Ws[kk][tx + 16 * j];
      #pragma unroll
      for (int i = 0; i < 4; ++i)
        #pragma unroll
        for (int j = 0; j < 4; ++j) acc[i][j] = fmaf(a[i], bb[j], acc[i][j]);
    }
    __syncthreads();
  }
  #pragma unroll
  for (int i = 0; i < 4; ++i) {
    int mr = m0 + ty + 16 * i;
    if (mr >= M) continue;
    int row = mr;
    if (REV_C) { int b = mr >> 11, t = mr & (L_SEQ - 1); row = (b << 11) | (L_SEQ - 1 - t); }
    #pragma unroll
    for (int j = 0; j < 4; ++j) {
      int n = n0 + tx + 16 * j;
      if (n >= N) continue;
      float v = acc[i][j];
      if (MODE == 0) {
        C0[(long)row * ldc + n] = v;
      } else if (MODE == 1) {
        if (n < D_INNER) C0[(long)row * D_INNER + n] = v;
        else             C1[(long)row * D_INNER + (n - D_INNER)] = v;
      } else if (MODE == 2) {
        v += bias[n];
        C0[(long)row * ldc + n] = softplusf(v);
      } else {
        C0[(long)row * ldc + n] += v;
      }
    }
  }
}

// causal depthwise conv (width 4) + bias + silu, in scan space
__global__ __launch_bounds__(256) void conv_silu(
    const float* __restrict__ xpre, // [2][B*L][D]
    const float* __restrict__ w_f, const float* __restrict__ b_f,
    const float* __restrict__ w_r, const float* __restrict__ b_r,
    float* __restrict__ xconv)
{
  long idx = (long)blockIdx.x * blockDim.x + threadIdx.x;
  const long total = 2L * B_SZ * L_SEQ * D_INNER;
  if (idx >= total) return;
  int d = (int)(idx % D_INNER);
  long r = idx / D_INNER;          // dir*B*L + b*L + t
  int t = (int)(r & (L_SEQ - 1));
  int dir = (int)(r >> 12);        // B*L = 4096
  const float* w  = dir ? w_r : w_f;
  const float* cb = dir ? b_r : b_f;
  float accv = cb[d];
  #pragma unroll
  for (int k = 0; k < 4; ++k) {
    int tt = t - 3 + k;
    if (tt >= 0) accv = fmaf(w[d * 4 + k], xpre[(r - 3 + k) * D_INNER + d], accv);
  }
  xconv[idx] = siluf(accv);
}

// selective scan: 1 thread per (dir, b, d); 16 states in registers.
__global__ __launch_bounds__(256) void scan_kernel(
    const float* __restrict__ dt,   // [2][B*L][D]
    float* __restrict__ xy,         // xconv in, y out (in place)
    const float* __restrict__ dbl,  // [2][B*L][80], cols 48..63=B, 64..79=C
    const float* __restrict__ z,
    const float* __restrict__ A_log_f, const float* __restrict__ A_log_r,
    const float* __restrict__ Ds_f, const float* __restrict__ Ds_r)
{
  const int tid = threadIdx.x;
  const int d = blockIdx.x * 256 + tid;
  const int b = blockIdx.y;
  const int dir = blockIdx.z;
  const float* A_log = dir ? A_log_r : A_log_f;
  const float* Ds = dir ? Ds_r : Ds_f;
  float Arow[D_STATE];
  #pragma unroll
  for (int n = 0; n < D_STATE; ++n) Arow[n] = -expf(A_log[d * D_STATE + n]);
  const float Dd = Ds[d];
  float h[D_STATE];
  #pragma unroll
  for (int n = 0; n < D_STATE; ++n) h[n] = 0.f;
  const long rowbase = ((long)dir * B_SZ + b) * L_SEQ;
  __shared__ float bc[64 * 32];
  for (int t0 = 0; t0 < L_SEQ; t0 += 64) {
    __syncthreads();
    for (int i = tid; i < 64 * 32; i += 256) {
      int tt = i >> 5, c = i & 31;
      bc[i] = dbl[(rowbase + t0 + tt) * 80 + 48 + c];
    }
    __syncthreads();
    for (int tj = 0; tj < 64; ++tj) {
      long off = (rowbase + t0 + tj) * D_INNER + d;
      float dtv = dt[off];
      float xv = xy[off];
      float zv = z[off];
      const float* Bt = &bc[tj * 32];
      float y = 0.f;
      float dtx = dtv * xv;
      #pragma unroll
      for (int n = 0; n < D_STATE; ++n) {
        float dA = __expf(dtv * Arow[n]);
        h[n] = fmaf(h[n], dA, dtx * Bt[n]);
        y = fmaf(h[n], Bt[16 + n], y);
      }
      y = fmaf(xv, Dd, y);
      y *= siluf(zv);
      xy[off] = y;
    }
  }
}

extern "C" void kernel_launch(void* const* d_in, const int* in_sizes, int n_in,
                              void* d_out, int out_size, void* d_ws, size_t ws_size,
                              hipStream_t stream) {
  const float* h        = (const float*)d_in[0];
  const float* in_proj[2] = {(const float*)d_in[1], (const float*)d_in[10]};
  const float* conv_w[2]  = {(const float*)d_in[2], (const float*)d_in[11]};
  const float* conv_b[2]  = {(const float*)d_in[3], (const float*)d_in[12]};
  const float* xproj[2]   = {(const float*)d_in[4], (const float*)d_in[13]};
  const float* dtw[2]     = {(const float*)d_in[5], (const float*)d_in[14]};
  const float* dtb[2]     = {(const float*)d_in[6], (const float*)d_in[15]};
  const float* A_log[2]   = {(const float*)d_in[7], (const float*)d_in[16]};
  const float* Dsk[2]     = {(const float*)d_in[8], (const float*)d_in[17]};
  const float* outp[2]    = {(const float*)d_in[9], (const float*)d_in[18]};
  float* out = (float*)d_out;
  float* ws = (float*)d_ws;

  const long S1 = (long)B_SZ * L_SEQ * D_INNER; // 6,291,456 floats per dir-plane
  float* xpre  = ws;            // [2][4096][1536]  (reused as dt after conv)
  float* zbuf  = ws + 2 * S1;   // [2][4096][1536]
  float* xconv = ws + 4 * S1;   // [2][4096][1536]  (becomes y in-place)
  float* dbl   = ws + 6 * S1;   // [2][4096][80]

  dim3 blk(256);
  const int M = B_SZ * L_SEQ;   // 4096

  // 1. in_proj -> split x (pre-conv) and z
  {
    dim3 grid((2 * D_INNER) / 64, M / 64);
    gemm_nt<1, 0, 0><<<grid, blk, 0, stream>>>(h, D_MODEL, in_proj[0], nullptr,
        xpre, zbuf, D_INNER, M, 2 * D_INNER, D_MODEL);
    gemm_nt<1, 1, 0><<<grid, blk, 0, stream>>>(h, D_MODEL, in_proj[1], nullptr,
        xpre + S1, zbuf + S1, D_INNER, M, 2 * D_INNER, D_MODEL);
  }
  // 2. conv + silu
  {
    long total = 2 * S1;
    conv_silu<<<dim3((unsigned)((total + 255) / 256)), blk, 0, stream>>>(
        xpre, conv_w[0], conv_b[0], conv_w[1], conv_b[1], xconv);
  }
  // 3. xproj -> dbl (dt_in | B | C)
  for (int dir = 0; dir < 2; ++dir) {
    dim3 grid(2, M / 64);
    gemm_nt<0, 0, 0><<<grid, blk, 0, stream>>>(xconv + dir * S1, D_INNER,
        xproj[dir], nullptr, dbl + (long)dir * M * 80, nullptr, 80,
        M, DT_RANK + 2 * D_STATE, D_INNER);
  }
  // 4. dtproj + bias + softplus -> dt (overwrites xpre)
  for (int dir = 0; dir < 2; ++dir) {
    dim3 grid(D_INNER / 64, M / 64);
    gemm_nt<2, 0, 0><<<grid, blk, 0, stream>>>(dbl + (long)dir * M * 80, 80,
        dtw[dir], dtb[dir], xpre + dir * S1, nullptr, D_INNER,
        M, D_INNER, DT_RANK);
  }
  // 5. selective scan (+ Dskip + silu(z) gating), y in place of xconv
  {
    dim3 grid(D_INNER / 256, B_SZ, 2);
    scan_kernel<<<grid, blk, 0, stream>>>(xpre, xconv, dbl, zbuf,
        A_log[0], A_log[1], Dsk[0], Dsk[1]);
  }
  // 6. out_proj fwd (assign), then out_proj rev (add, reversed rows)
  {
    dim3 grid(D_MODEL / 64, M / 64);
    gemm_nt<0, 0, 0><<<grid, blk, 0, stream>>>(xconv, D_INNER, outp[0], nullptr,
        out, nullptr, D_MODEL, M, D_MODEL, D_INNER);
    gemm_nt<3, 0, 1><<<grid, blk, 0, stream>>>(xconv + S1, D_INNER, outp[1], nullptr,
        out, nullptr, D_MODEL, M, D_MODEL, D_INNER);
  }
}

// Round 2
// 1505.823 us; speedup vs baseline: 2.3044x; 2.3044x over previous
//
#include <hip/hip_runtime.h>
#include <hip/hip_bf16.h>
#include <math.h>

#define L_SEQ 2048
#define B_SZ 2
#define D_MODEL 768
#define D_INNER 1536
#define D_STATE 16
#define DT_RANK 48
#define TC 64
#define NC (L_SEQ / TC)          // 32 chunks
#define NDG (D_INNER / 256)      // 6 d-groups

static __device__ __forceinline__ float siluf(float v) {
  return v / (1.0f + __expf(-v));
}
static __device__ __forceinline__ float softplusf(float v) {
  return fmaxf(v, 0.0f) + log1pf(__expf(-fabsf(v)));
}

// ---------------- 64x64 tile GEMM (small-N shapes: xproj) ----------------
template<int MODE, int REV_A, int REV_C>
__global__ __launch_bounds__(256) void gemm_nt(
    const float* __restrict__ A, int lda,
    const float* __restrict__ W,
    const float* __restrict__ bias,
    float* __restrict__ C0, float* __restrict__ C1, int ldc,
    int M, int N, int K)
{
  __shared__ float As[16][65];
  __shared__ float Ws[16][65];
  const int tid = threadIdx.x;
  const int m0 = blockIdx.y * 64, n0 = blockIdx.x * 64;
  const int tx = tid & 15, ty = tid >> 4;
  const int lk = tid & 15, lr = tid >> 4;
  float acc[4][4] = {};
  for (int k0 = 0; k0 < K; k0 += 16) {
    #pragma unroll
    for (int i = 0; i < 4; ++i) {
      int m = lr + 16 * i;
      int mr = m0 + m;
      float v = 0.f;
      if (mr < M) {
        int row = mr;
        if (REV_A) { int b = mr >> 11, t = mr & (L_SEQ - 1); row = (b << 11) | (L_SEQ - 1 - t); }
        v = A[(long)row * lda + k0 + lk];
      }
      As[lk][m] = v;
    }
    #pragma unroll
    for (int i = 0; i < 4; ++i) {
      int n = lr + 16 * i;
      int nr = n0 + n;
      float v = 0.f;
      if (nr < N) v = W[(long)nr * K + k0 + lk];
      Ws[lk][n] = v;
    }
    __syncthreads();
    #pragma unroll
    for (int kk = 0; kk < 16; ++kk) {
      float a[4], bb[4];
      #pragma unroll
      for (int i = 0; i < 4; ++i) a[i] = As[kk][ty + 16 * i];
      #pragma unroll
      for (int j = 0; j < 4; ++j) bb[j] = Ws[kk][tx + 16 * j];
      #pragma unroll
      for (int i = 0; i < 4; ++i)
        #pragma unroll
        for (int j = 0; j < 4; ++j) acc[i][j] = fmaf(a[i], bb[j], acc[i][j]);
    }
    __syncthreads();
  }
  #pragma unroll
  for (int i = 0; i < 4; ++i) {
    int mr = m0 + ty + 16 * i;
    if (mr >= M) continue;
    int row = mr;
    if (REV_C) { int b = mr >> 11, t = mr & (L_SEQ - 1); row = (b << 11) | (L_SEQ - 1 - t); }
    #pragma unroll
    for (int j = 0; j < 4; ++j) {
      int n = n0 + tx + 16 * j;
      if (n >= N) continue;
      float v = acc[i][j];
      if (MODE == 0) {
        C0[(long)row * ldc + n] = v;
      } else if (MODE == 1) {
        if (n < D_INNER) C0[(long)row * D_INNER + n] = v;
        else             C1[(long)row * D_INNER + (n - D_INNER)] = v;
      } else if (MODE == 2) {
        v += bias[n];
        C0[(long)row * ldc + n] = softplusf(v);
      } else {
        C0[(long)row * ldc + n] += v;
      }
    }
  }
}

// ---------------- 128x128 tile GEMM, 8x8 per thread (big shapes) ----------
// Requires: M%128==0, N%128==0, K%16==0 (all true for shapes used).
template<int MODE, int REV_A, int REV_C>
__global__ __launch_bounds__(256) void gemm128(
    const float* __restrict__ A, int lda,
    const float* __restrict__ W,
    const float* __restrict__ bias,
    float* __restrict__ C0, float* __restrict__ C1, int ldc,
    int M, int N, int K)
{
  __shared__ float As[16][132];
  __shared__ float Ws[16][132];
  const int tid = threadIdx.x;
  const int m0 = blockIdx.y * 128, n0 = blockIdx.x * 128;
  const int tx = tid & 15, ty = tid >> 4;
  const int lm = tid >> 1;          // 0..127
  const int lk = (tid & 1) * 8;     // 0 or 8
  int rowA = m0 + lm;
  if (REV_A) { int b = rowA >> 11, t = rowA & (L_SEQ - 1); rowA = (b << 11) | (L_SEQ - 1 - t); }
  const float* Aptr = A + (long)rowA * lda + lk;
  const float* Wptr = W + (long)(n0 + lm) * K + lk;
  float acc[8][8] = {};
  for (int k0 = 0; k0 < K; k0 += 16) {
    float4 a0 = *(const float4*)(Aptr + k0);
    float4 a1 = *(const float4*)(Aptr + k0 + 4);
    float4 w0 = *(const float4*)(Wptr + k0);
    float4 w1 = *(const float4*)(Wptr + k0 + 4);
    As[lk + 0][lm] = a0.x; As[lk + 1][lm] = a0.y; As[lk + 2][lm] = a0.z; As[lk + 3][lm] = a0.w;
    As[lk + 4][lm] = a1.x; As[lk + 5][lm] = a1.y; As[lk + 6][lm] = a1.z; As[lk + 7][lm] = a1.w;
    Ws[lk + 0][lm] = w0.x; Ws[lk + 1][lm] = w0.y; Ws[lk + 2][lm] = w0.z; Ws[lk + 3][lm] = w0.w;
    Ws[lk + 4][lm] = w1.x; Ws[lk + 5][lm] = w1.y; Ws[lk + 6][lm] = w1.z; Ws[lk + 7][lm] = w1.w;
    __syncthreads();
    #pragma unroll
    for (int kk = 0; kk < 16; ++kk) {
      float4 av0 = *(const float4*)&As[kk][ty * 4];
      float4 av1 = *(const float4*)&As[kk][64 + ty * 4];
      float4 bv0 = *(const float4*)&Ws[kk][tx * 4];
      float4 bv1 = *(const float4*)&Ws[kk][64 + tx * 4];
      float am[8] = {av0.x, av0.y, av0.z, av0.w, av1.x, av1.y, av1.z, av1.w};
      float bn[8] = {bv0.x, bv0.y, bv0.z, bv0.w, bv1.x, bv1.y, bv1.z, bv1.w};
      #pragma unroll
      for (int i = 0; i < 8; ++i)
        #pragma unroll
        for (int j = 0; j < 8; ++j) acc[i][j] = fmaf(am[i], bn[j], acc[i][j]);
    }
    __syncthreads();
  }
  #pragma unroll
  for (int i = 0; i < 8; ++i) {
    int mr = m0 + ty * 4 + (i & 3) + ((i >> 2) << 6);
    int row = mr;
    if (REV_C) { int b = mr >> 11, t = mr & (L_SEQ - 1); row = (b << 11) | (L_SEQ - 1 - t); }
    #pragma unroll
    for (int j = 0; j < 8; ++j) {
      int n = n0 + tx * 4 + (j & 3) + ((j >> 2) << 6);
      float v = acc[i][j];
      if (MODE == 0) {
        C0[(long)row * ldc + n] = v;
      } else if (MODE == 1) {
        if (n < D_INNER) C0[(long)row * D_INNER + n] = v;
        else             C1[(long)row * D_INNER + (n - D_INNER)] = v;
      } else if (MODE == 2) {
        v += bias[n];
        C0[(long)row * ldc + n] = softplusf(v);
      } else {
        C0[(long)row * ldc + n] += v;
      }
    }
  }
}

// ---------------- causal depthwise conv (w=4) + bias + silu ----------------
__global__ __launch_bounds__(256) void conv_silu(
    const float* __restrict__ xpre,
    const float* __restrict__ w_f, const float* __restrict__ b_f,
    const float* __restrict__ w_r, const float* __restrict__ b_r,
    float* __restrict__ xconv)
{
  long idx = (long)blockIdx.x * blockDim.x + threadIdx.x;
  const long total = 2L * B_SZ * L_SEQ * D_INNER;
  if (idx >= total) return;
  int d = (int)(idx % D_INNER);
  long r = idx / D_INNER;
  int t = (int)(r & (L_SEQ - 1));
  int dir = (int)(r >> 12);
  const float* w  = dir ? w_r : w_f;
  const float* cb = dir ? b_r : b_f;
  float accv = cb[d];
  #pragma unroll
  for (int k = 0; k < 4; ++k) {
    int tt = t - 3 + k;
    if (tt >= 0) accv = fmaf(w[d * 4 + k], xpre[(r - 3 + k) * D_INNER + d], accv);
  }
  xconv[idx] = siluf(accv);
}

// ---------------- chunked selective scan ----------------
// Pass 1: per-chunk local scan from h=0; record final local state S and
// per-state decay product P.
__global__ __launch_bounds__(256) void scan_part1(
    const float* __restrict__ dt, const float* __restrict__ x,
    const float* __restrict__ dbl,
    const float* __restrict__ A_log_f, const float* __restrict__ A_log_r,
    float* __restrict__ stateS, float* __restrict__ stateP)
{
  const int tid = threadIdx.x;
  const int chunk = blockIdx.x / NDG;
  const int d = (blockIdx.x % NDG) * 256 + tid;
  const int b = blockIdx.y, dir = blockIdx.z;
  const float* A_log = dir ? A_log_r : A_log_f;
  float Arow[D_STATE];
  #pragma unroll
  for (int n = 0; n < D_STATE; ++n) Arow[n] = -expf(A_log[d * D_STATE + n]);
  float h[D_STATE], P[D_STATE];
  #pragma unroll
  for (int n = 0; n < D_STATE; ++n) { h[n] = 0.f; P[n] = 1.f; }
  const long rowbase = ((long)dir * B_SZ + b) * L_SEQ + (long)chunk * TC;
  __shared__ float bt[TC][D_STATE];
  for (int i = tid; i < TC * D_STATE; i += 256) {
    int t = i >> 4, n = i & 15;
    bt[t][n] = dbl[(rowbase + t) * 80 + 48 + n];
  }
  __syncthreads();
  for (int tj = 0; tj < TC; ++tj) {
    long off = (rowbase + tj) * D_INNER + d;
    float dtv = dt[off];
    float xv = x[off];
    float dtx = dtv * xv;
    #pragma unroll
    for (int n = 0; n < D_STATE; ++n) {
      float dA = __expf(dtv * Arow[n]);
      P[n] *= dA;
      h[n] = fmaf(h[n], dA, dtx * bt[tj][n]);
    }
  }
  long base = ((((long)dir * B_SZ + b) * NC + chunk) * D_INNER + d) * D_STATE;
  #pragma unroll
  for (int n = 0; n < D_STATE; ++n) { stateS[base + n] = h[n]; stateP[base + n] = P[n]; }
}

// Pass 2: sequential fix-up across chunks; overwrite stateS with h_in per chunk.
__global__ __launch_bounds__(256) void scan_fix(
    float* __restrict__ stateS, const float* __restrict__ stateP)
{
  const long idx = (long)blockIdx.x * 256 + threadIdx.x;   // 2*B*D*16 threads
  const int DN = D_INNER * D_STATE;
  const long dirb = idx / DN;
  const int dn = (int)(idx % DN);
  long base = dirb * NC * DN + dn;
  float h = 0.f;
  for (int c = 0; c < NC; ++c) {
    long o = base + (long)c * DN;
    float S = stateS[o];
    float Pc = stateP[o];
    stateS[o] = h;
    h = fmaf(h, Pc, S);
  }
}

// Pass 3: rerun exact recurrence from corrected h_in; produce gated y in place.
__global__ __launch_bounds__(256) void scan_part2(
    const float* __restrict__ dt, float* __restrict__ xy,
    const float* __restrict__ dbl, const float* __restrict__ z,
    const float* __restrict__ A_log_f, const float* __restrict__ A_log_r,
    const float* __restrict__ Ds_f, const float* __restrict__ Ds_r,
    const float* __restrict__ stateS)
{
  const int tid = threadIdx.x;
  const int chunk = blockIdx.x / NDG;
  const int d = (blockIdx.x % NDG) * 256 + tid;
  const int b = blockIdx.y, dir = blockIdx.z;
  const float* A_log = dir ? A_log_r : A_log_f;
  const float* Ds = dir ? Ds_r : Ds_f;
  float Arow[D_STATE];
  #pragma unroll
  for (int n = 0; n < D_STATE; ++n) Arow[n] = -expf(A_log[d * D_STATE + n]);
  const float Dd = Ds[d];
  float h[D_STATE];
  long sbase = ((((long)dir * B_SZ + b) * NC + chunk) * D_INNER + d) * D_STATE;
  #pragma unroll
  for (int n = 0; n < D_STATE; ++n) h[n] = stateS[sbase + n];
  const long rowbase = ((long)dir * B_SZ + b) * L_SEQ + (long)chunk * TC;
  __shared__ float bc[TC][2 * D_STATE];
  for (int i = tid; i < TC * 2 * D_STATE; i += 256) {
    int t = i >> 5, n = i & 31;
    bc[t][n] = dbl[(rowbase + t) * 80 + 48 + n];
  }
  __syncthreads();
  for (int tj = 0; tj < TC; ++tj) {
    long off = (rowbase + tj) * D_INNER + d;
    float dtv = dt[off];
    float xv = xy[off];
    float zv = z[off];
    float dtx = dtv * xv;
    float y = 0.f;
    #pragma unroll
    for (int n = 0; n < D_STATE; ++n) {
      float dA = __expf(dtv * Arow[n]);
      h[n] = fmaf(h[n], dA, dtx * bc[tj][n]);
      y = fmaf(h[n], bc[tj][16 + n], y);
    }
    y = fmaf(xv, Dd, y);
    y *= siluf(zv);
    xy[off] = y;
  }
}

extern "C" void kernel_launch(void* const* d_in, const int* in_sizes, int n_in,
                              void* d_out, int out_size, void* d_ws, size_t ws_size,
                              hipStream_t stream) {
  const float* h        = (const float*)d_in[0];
  const float* in_proj[2] = {(const float*)d_in[1], (const float*)d_in[10]};
  const float* conv_w[2]  = {(const float*)d_in[2], (const float*)d_in[11]};
  const float* conv_b[2]  = {(const float*)d_in[3], (const float*)d_in[12]};
  const float* xproj[2]   = {(const float*)d_in[4], (const float*)d_in[13]};
  const float* dtw[2]     = {(const float*)d_in[5], (const float*)d_in[14]};
  const float* dtb[2]     = {(const float*)d_in[6], (const float*)d_in[15]};
  const float* A_log[2]   = {(const float*)d_in[7], (const float*)d_in[16]};
  const float* Dsk[2]     = {(const float*)d_in[8], (const float*)d_in[17]};
  const float* outp[2]    = {(const float*)d_in[9], (const float*)d_in[18]};
  float* out = (float*)d_out;
  float* ws = (float*)d_ws;

  const long S1 = (long)B_SZ * L_SEQ * D_INNER;
  float* xpre  = ws;            // [2][4096][1536]  (becomes dt)
  float* zbuf  = ws + 2 * S1;
  float* xconv = ws + 4 * S1;   // (becomes y in-place)
  float* dbl   = ws + 6 * S1;   // [2][4096][80]
  float* stS   = dbl + 2L * B_SZ * L_SEQ * 80;          // [2][2][NC][D][16]
  float* stP   = stS + 2L * B_SZ * NC * D_INNER * D_STATE;

  dim3 blk(256);
  const int M = B_SZ * L_SEQ;   // 4096

  // 1. in_proj -> x (pre-conv) and z
  {
    dim3 grid((2 * D_INNER) / 128, M / 128);
    gemm128<1, 0, 0><<<grid, blk, 0, stream>>>(h, D_MODEL, in_proj[0], nullptr,
        xpre, zbuf, D_INNER, M, 2 * D_INNER, D_MODEL);
    gemm128<1, 1, 0><<<grid, blk, 0, stream>>>(h, D_MODEL, in_proj[1], nullptr,
        xpre + S1, zbuf + S1, D_INNER, M, 2 * D_INNER, D_MODEL);
  }
  // 2. conv + silu
  {
    long total = 2 * S1;
    conv_silu<<<dim3((unsigned)((total + 255) / 256)), blk, 0, stream>>>(
        xpre, conv_w[0], conv_b[0], conv_w[1], conv_b[1], xconv);
  }
  // 3. xproj -> dbl (dt_in | B | C)
  for (int dir = 0; dir < 2; ++dir) {
    dim3 grid(2, M / 64);
    gemm_nt<0, 0, 0><<<grid, blk, 0, stream>>>(xconv + dir * S1, D_INNER,
        xproj[dir], nullptr, dbl + (long)dir * M * 80, nullptr, 80,
        M, DT_RANK + 2 * D_STATE, D_INNER);
  }
  // 4. dtproj + bias + softplus -> dt
  for (int dir = 0; dir < 2; ++dir) {
    dim3 grid(D_INNER / 128, M / 128);
    gemm128<2, 0, 0><<<grid, blk, 0, stream>>>(dbl + (long)dir * M * 80, 80,
        dtw[dir], dtb[dir], xpre + dir * S1, nullptr, D_INNER,
        M, D_INNER, DT_RANK);
  }
  // 5. chunked scan
  {
    dim3 grid1(NC * NDG, B_SZ, 2);
    scan_part1<<<grid1, blk, 0, stream>>>(xpre, xconv, dbl,
        A_log[0], A_log[1], stS, stP);
    long nfix = 2L * B_SZ * D_INNER * D_STATE;
    scan_fix<<<dim3((unsigned)(nfix / 256)), blk, 0, stream>>>(stS, stP);
    scan_part2<<<grid1, blk, 0, stream>>>(xpre, xconv, dbl, zbuf,
        A_log[0], A_log[1], Dsk[0], Dsk[1], stS);
  }
  // 6. out_proj fwd (assign) + rev (add, reversed rows)
  {
    dim3 grid(D_MODEL / 128, M / 128);
    gemm128<0, 0, 0><<<grid, blk, 0, stream>>>(xconv, D_INNER, outp[0], nullptr,
        out, nullptr, D_MODEL, M, D_MODEL, D_INNER);
    gemm128<3, 0, 1><<<grid, blk, 0, stream>>>(xconv + S1, D_INNER, outp[1], nullptr,
        out, nullptr, D_MODEL, M, D_MODEL, D_INNER);
  }
}

// Round 3
// 683.541 us; speedup vs baseline: 5.0765x; 2.2030x over previous
//
#include <hip/hip_runtime.h>
#include <hip/hip_bf16.h>
#include <math.h>

#define L_SEQ 2048
#define B_SZ 2
#define D_MODEL 768
#define D_INNER 1536
#define D_STATE 16
#define DT_RANK 48
#define TC 64
#define NC (L_SEQ / TC)          // 32 chunks
#define NDG (D_INNER / 256)      // 6 d-groups
#define NSPL 4
#define KCH (D_INNER / NSPL)     // 384

typedef short bf16x8 __attribute__((ext_vector_type(8)));
typedef float f32x4 __attribute__((ext_vector_type(4)));

static __device__ __forceinline__ float siluf(float v) {
  return v / (1.0f + __expf(-v));
}
static __device__ __forceinline__ float softplusf(float v) {
  return fmaxf(v, 0.0f) + log1pf(__expf(-fabsf(v)));
}
static __device__ __forceinline__ unsigned short f2bf_rn(float v) {
  unsigned u = __float_as_uint(v);
  u = (u + 0x7fff + ((u >> 16) & 1)) >> 16;
  return (unsigned short)u;
}

// ---------------- MFMA GEMM, fp32-accurate via 3-term hi/lo bf16 ----------
// C = A @ W^T. A [M][lda] fp32, W [N][K] fp32. 128x128 tile, 4 waves.
// MODE 0: C0 = acc; MODE 1: xz split; MODE 3: C0 += acc.
template<int MODE, int REV_A, int REV_C>
__global__ __launch_bounds__(256) void gemm_mfma(
    const float* __restrict__ A, int lda,
    const float* __restrict__ W,
    float* __restrict__ C0, float* __restrict__ C1, int ldc,
    int M, int N, int K)
{
  __shared__ unsigned short Ah[128 * 32], Al[128 * 32];
  __shared__ unsigned short Wh[128 * 32], Wl[128 * 32];
  const int tid = threadIdx.x;
  const int m0 = blockIdx.y * 128, n0 = blockIdx.x * 128;
  const int lane = tid & 63, w = tid >> 6;
  const int wr = w >> 1, wc = w & 1;
  // staging: thread -> row (0..127), k-half (0 or 16)
  const int srow = tid >> 1;
  const int sk = (tid & 1) * 16;
  int rowA = m0 + srow;
  if (REV_A) { int b = rowA >> 11, t = rowA & (L_SEQ - 1); rowA = (b << 11) | (L_SEQ - 1 - t); }
  const float* Ap = A + (long)rowA * lda + sk;
  const float* Wp = W + (long)(n0 + srow) * K + sk;

  f32x4 acc[4][4];
  #pragma unroll
  for (int i = 0; i < 4; ++i)
    #pragma unroll
    for (int j = 0; j < 4; ++j) acc[i][j] = (f32x4){0.f, 0.f, 0.f, 0.f};

  for (int k0 = 0; k0 < K; k0 += 32) {
    float4 av[4], wv[4];
    #pragma unroll
    for (int q = 0; q < 4; ++q) {
      av[q] = *(const float4*)(Ap + k0 + q * 4);
      wv[q] = *(const float4*)(Wp + k0 + q * 4);
    }
    unsigned short ah[16], al[16], wh[16], wl[16];
    #pragma unroll
    for (int q = 0; q < 4; ++q) {
      float va[4] = {av[q].x, av[q].y, av[q].z, av[q].w};
      float vw[4] = {wv[q].x, wv[q].y, wv[q].z, wv[q].w};
      #pragma unroll
      for (int e = 0; e < 4; ++e) {
        int i = q * 4 + e;
        unsigned short h = f2bf_rn(va[e]);
        ah[i] = h;
        al[i] = f2bf_rn(va[e] - __uint_as_float(((unsigned)h) << 16));
        unsigned short h2 = f2bf_rn(vw[e]);
        wh[i] = h2;
        wl[i] = f2bf_rn(vw[e] - __uint_as_float(((unsigned)h2) << 16));
      }
    }
    __syncthreads();   // previous iter's frag reads done
    const int swz = (srow >> 1) & 3;
    #pragma unroll
    for (int s = 0; s < 2; ++s) {
      int slot = (sk >> 3) + s;   // 0/1 or 2/3
      int off = srow * 32 + ((slot ^ swz) * 8);
      *(bf16x8*)&Ah[off] = *(const bf16x8*)&ah[s * 8];
      *(bf16x8*)&Al[off] = *(const bf16x8*)&al[s * 8];
      *(bf16x8*)&Wh[off] = *(const bf16x8*)&wh[s * 8];
      *(bf16x8*)&Wl[off] = *(const bf16x8*)&wl[s * 8];
    }
    __syncthreads();
    const int fr = lane & 15, slot = lane >> 4;
    bf16x8 afh[4], afl[4];
    #pragma unroll
    for (int fi = 0; fi < 4; ++fi) {
      int r = wr * 64 + fi * 16 + fr;
      int off = r * 32 + ((slot ^ ((r >> 1) & 3)) * 8);
      afh[fi] = *(const bf16x8*)&Ah[off];
      afl[fi] = *(const bf16x8*)&Al[off];
    }
    #pragma unroll
    for (int fj = 0; fj < 4; ++fj) {
      int r = wc * 64 + fj * 16 + fr;
      int off = r * 32 + ((slot ^ ((r >> 1) & 3)) * 8);
      bf16x8 wfh = *(const bf16x8*)&Wh[off];
      bf16x8 wfl = *(const bf16x8*)&Wl[off];
      #pragma unroll
      for (int fi = 0; fi < 4; ++fi) {
        acc[fi][fj] = __builtin_amdgcn_mfma_f32_16x16x32_bf16(afh[fi], wfh, acc[fi][fj], 0, 0, 0);
        acc[fi][fj] = __builtin_amdgcn_mfma_f32_16x16x32_bf16(afh[fi], wfl, acc[fi][fj], 0, 0, 0);
        acc[fi][fj] = __builtin_amdgcn_mfma_f32_16x16x32_bf16(afl[fi], wfh, acc[fi][fj], 0, 0, 0);
      }
    }
  }
  // epilogue: D[row=(lane>>4)*4+j][col=lane&15] per 16x16 frag
  const int fcol = lane & 15, rgrp = lane >> 4;
  #pragma unroll
  for (int fi = 0; fi < 4; ++fi) {
    #pragma unroll
    for (int j = 0; j < 4; ++j) {
      int mr = m0 + wr * 64 + fi * 16 + rgrp * 4 + j;
      int row = mr;
      if (REV_C) { int b = mr >> 11, t = mr & (L_SEQ - 1); row = (b << 11) | (L_SEQ - 1 - t); }
      #pragma unroll
      for (int fj = 0; fj < 4; ++fj) {
        int n = n0 + wc * 64 + fj * 16 + fcol;
        float v = acc[fi][fj][j];
        if (MODE == 0) {
          C0[(long)row * ldc + n] = v;
        } else if (MODE == 1) {
          if (n < D_INNER) C0[(long)row * D_INNER + n] = v;
          else             C1[(long)row * D_INNER + (n - D_INNER)] = v;
        } else {
          C0[(long)row * ldc + n] += v;
        }
      }
    }
  }
}

// ---------------- 128x128 fp32 VALU GEMM (dtproj only: K=48) --------------
template<int MODE>
__global__ __launch_bounds__(256) void gemm128(
    const float* __restrict__ A, int lda,
    const float* __restrict__ W,
    const float* __restrict__ bias,
    float* __restrict__ C0, int ldc,
    int M, int N, int K)
{
  __shared__ float As[16][132];
  __shared__ float Ws[16][132];
  const int tid = threadIdx.x;
  const int m0 = blockIdx.y * 128, n0 = blockIdx.x * 128;
  const int tx = tid & 15, ty = tid >> 4;
  const int lm = tid >> 1;
  const int lk = (tid & 1) * 8;
  const float* Aptr = A + (long)(m0 + lm) * lda + lk;
  const float* Wptr = W + (long)(n0 + lm) * K + lk;
  float acc[8][8] = {};
  for (int k0 = 0; k0 < K; k0 += 16) {
    float4 a0 = *(const float4*)(Aptr + k0);
    float4 a1 = *(const float4*)(Aptr + k0 + 4);
    float4 w0 = *(const float4*)(Wptr + k0);
    float4 w1 = *(const float4*)(Wptr + k0 + 4);
    As[lk + 0][lm] = a0.x; As[lk + 1][lm] = a0.y; As[lk + 2][lm] = a0.z; As[lk + 3][lm] = a0.w;
    As[lk + 4][lm] = a1.x; As[lk + 5][lm] = a1.y; As[lk + 6][lm] = a1.z; As[lk + 7][lm] = a1.w;
    Ws[lk + 0][lm] = w0.x; Ws[lk + 1][lm] = w0.y; Ws[lk + 2][lm] = w0.z; Ws[lk + 3][lm] = w0.w;
    Ws[lk + 4][lm] = w1.x; Ws[lk + 5][lm] = w1.y; Ws[lk + 6][lm] = w1.z; Ws[lk + 7][lm] = w1.w;
    __syncthreads();
    #pragma unroll
    for (int kk = 0; kk < 16; ++kk) {
      float4 av0 = *(const float4*)&As[kk][ty * 4];
      float4 av1 = *(const float4*)&As[kk][64 + ty * 4];
      float4 bv0 = *(const float4*)&Ws[kk][tx * 4];
      float4 bv1 = *(const float4*)&Ws[kk][64 + tx * 4];
      float am[8] = {av0.x, av0.y, av0.z, av0.w, av1.x, av1.y, av1.z, av1.w};
      float bn[8] = {bv0.x, bv0.y, bv0.z, bv0.w, bv1.x, bv1.y, bv1.z, bv1.w};
      #pragma unroll
      for (int i = 0; i < 8; ++i)
        #pragma unroll
        for (int j = 0; j < 8; ++j) acc[i][j] = fmaf(am[i], bn[j], acc[i][j]);
    }
    __syncthreads();
  }
  #pragma unroll
  for (int i = 0; i < 8; ++i) {
    int row = m0 + ty * 4 + (i & 3) + ((i >> 2) << 6);
    #pragma unroll
    for (int j = 0; j < 8; ++j) {
      int n = n0 + tx * 4 + (j & 3) + ((j >> 2) << 6);
      float v = acc[i][j];
      if (MODE == 2) { v += bias[n]; v = softplusf(v); }
      C0[(long)row * ldc + n] = v;
    }
  }
}

// ---------------- xproj: split-K tall-skinny GEMM (N=80) ------------------
__global__ __launch_bounds__(256) void xproj_splitk(
    const float* __restrict__ X,       // [2][B*L][D_INNER]
    const float* __restrict__ xproj_f, const float* __restrict__ xproj_r,
    float* __restrict__ partial)       // [2][NSPL][B*L][80]
{
  const int tid = threadIdx.x;
  const int m0 = blockIdx.x * 64;
  const int kz = blockIdx.y;
  const int dir = blockIdx.z;
  const float* W = dir ? xproj_r : xproj_f;
  const float* A = X + (long)dir * B_SZ * L_SEQ * D_INNER;
  __shared__ float As[16][65];
  __shared__ float Ws[16][81];
  const int lk = tid & 15, lr = tid >> 4;
  const int tx = tid & 15, ty = tid >> 4;
  float acc[4][5] = {};
  const int kbase = kz * KCH;
  for (int k0 = 0; k0 < KCH; k0 += 16) {
    #pragma unroll
    for (int i = 0; i < 4; ++i)
      As[lk][lr + 16 * i] = A[(long)(m0 + lr + 16 * i) * D_INNER + kbase + k0 + lk];
    for (int r = lr; r < 80; r += 16)
      Ws[lk][r] = W[(long)r * D_INNER + kbase + k0 + lk];
    __syncthreads();
    #pragma unroll
    for (int kk = 0; kk < 16; ++kk) {
      float a[4], b[5];
      #pragma unroll
      for (int i = 0; i < 4; ++i) a[i] = As[kk][ty + 16 * i];
      #pragma unroll
      for (int j = 0; j < 5; ++j) b[j] = Ws[kk][tx * 5 + j];
      #pragma unroll
      for (int i = 0; i < 4; ++i)
        #pragma unroll
        for (int j = 0; j < 5; ++j) acc[i][j] = fmaf(a[i], b[j], acc[i][j]);
    }
    __syncthreads();
  }
  float* P = partial + (((long)dir * NSPL + kz) * (B_SZ * L_SEQ) + m0) * 80;
  #pragma unroll
  for (int i = 0; i < 4; ++i)
    #pragma unroll
    for (int j = 0; j < 5; ++j)
      P[(long)(ty + 16 * i) * 80 + tx * 5 + j] = acc[i][j];
}

__global__ __launch_bounds__(256) void xproj_reduce(
    const float* __restrict__ partial, float* __restrict__ dbl)
{
  long idx = (long)blockIdx.x * 256 + threadIdx.x;
  const long plane = (long)B_SZ * L_SEQ * 80;
  long dir = idx / plane;
  long rc = idx % plane;
  const float* P = partial + dir * NSPL * plane + rc;
  float s = 0.f;
  #pragma unroll
  for (int z = 0; z < NSPL; ++z) s += P[z * plane];
  dbl[idx] = s;
}

// ---------------- causal depthwise conv (w=4) + bias + silu ---------------
__global__ __launch_bounds__(256) void conv_silu(
    const float* __restrict__ xpre,
    const float* __restrict__ w_f, const float* __restrict__ b_f,
    const float* __restrict__ w_r, const float* __restrict__ b_r,
    float* __restrict__ xconv)
{
  long idx = (long)blockIdx.x * blockDim.x + threadIdx.x;
  const long total = 2L * B_SZ * L_SEQ * D_INNER;
  if (idx >= total) return;
  int d = (int)(idx % D_INNER);
  long r = idx / D_INNER;
  int t = (int)(r & (L_SEQ - 1));
  int dir = (int)(r >> 12);
  const float* w  = dir ? w_r : w_f;
  const float* cb = dir ? b_r : b_f;
  float accv = cb[d];
  #pragma unroll
  for (int k = 0; k < 4; ++k) {
    int tt = t - 3 + k;
    if (tt >= 0) accv = fmaf(w[d * 4 + k], xpre[(r - 3 + k) * D_INNER + d], accv);
  }
  xconv[idx] = siluf(accv);
}

// ---------------- chunked selective scan ----------------
__global__ __launch_bounds__(256) void scan_part1(
    const float* __restrict__ dt, const float* __restrict__ x,
    const float* __restrict__ dbl,
    const float* __restrict__ A_log_f, const float* __restrict__ A_log_r,
    float* __restrict__ stateS, float* __restrict__ stateP)
{
  const int tid = threadIdx.x;
  const int chunk = blockIdx.x / NDG;
  const int d = (blockIdx.x % NDG) * 256 + tid;
  const int b = blockIdx.y, dir = blockIdx.z;
  const float* A_log = dir ? A_log_r : A_log_f;
  float Arow[D_STATE];
  #pragma unroll
  for (int n = 0; n < D_STATE; ++n) Arow[n] = -expf(A_log[d * D_STATE + n]);
  float h[D_STATE], P[D_STATE];
  #pragma unroll
  for (int n = 0; n < D_STATE; ++n) { h[n] = 0.f; P[n] = 1.f; }
  const long rowbase = ((long)dir * B_SZ + b) * L_SEQ + (long)chunk * TC;
  __shared__ float bt[TC][D_STATE];
  for (int i = tid; i < TC * D_STATE; i += 256) {
    int t = i >> 4, n = i & 15;
    bt[t][n] = dbl[(rowbase + t) * 80 + 48 + n];
  }
  __syncthreads();
  for (int tj = 0; tj < TC; ++tj) {
    long off = (rowbase + tj) * D_INNER + d;
    float dtv = dt[off];
    float xv = x[off];
    float dtx = dtv * xv;
    #pragma unroll
    for (int n = 0; n < D_STATE; ++n) {
      float dA = __expf(dtv * Arow[n]);
      P[n] *= dA;
      h[n] = fmaf(h[n], dA, dtx * bt[tj][n]);
    }
  }
  long base = ((((long)dir * B_SZ + b) * NC + chunk) * D_INNER + d) * D_STATE;
  #pragma unroll
  for (int n = 0; n < D_STATE; ++n) { stateS[base + n] = h[n]; stateP[base + n] = P[n]; }
}

__global__ __launch_bounds__(256) void scan_fix(
    float* __restrict__ stateS, const float* __restrict__ stateP)
{
  const long idx = (long)blockIdx.x * 256 + threadIdx.x;
  const int DN = D_INNER * D_STATE;
  const long dirb = idx / DN;
  const int dn = (int)(idx % DN);
  long base = dirb * NC * DN + dn;
  float h = 0.f;
  for (int c = 0; c < NC; ++c) {
    long o = base + (long)c * DN;
    float S = stateS[o];
    float Pc = stateP[o];
    stateS[o] = h;
    h = fmaf(h, Pc, S);
  }
}

__global__ __launch_bounds__(256) void scan_part2(
    const float* __restrict__ dt, float* __restrict__ xy,
    const float* __restrict__ dbl, const float* __restrict__ z,
    const float* __restrict__ A_log_f, const float* __restrict__ A_log_r,
    const float* __restrict__ Ds_f, const float* __restrict__ Ds_r,
    const float* __restrict__ stateS)
{
  const int tid = threadIdx.x;
  const int chunk = blockIdx.x / NDG;
  const int d = (blockIdx.x % NDG) * 256 + tid;
  const int b = blockIdx.y, dir = blockIdx.z;
  const float* A_log = dir ? A_log_r : A_log_f;
  const float* Ds = dir ? Ds_r : Ds_f;
  float Arow[D_STATE];
  #pragma unroll
  for (int n = 0; n < D_STATE; ++n) Arow[n] = -expf(A_log[d * D_STATE + n]);
  const float Dd = Ds[d];
  float h[D_STATE];
  long sbase = ((((long)dir * B_SZ + b) * NC + chunk) * D_INNER + d) * D_STATE;
  #pragma unroll
  for (int n = 0; n < D_STATE; ++n) h[n] = stateS[sbase + n];
  const long rowbase = ((long)dir * B_SZ + b) * L_SEQ + (long)chunk * TC;
  __shared__ float bc[TC][2 * D_STATE];
  for (int i = tid; i < TC * 2 * D_STATE; i += 256) {
    int t = i >> 5, n = i & 31;
    bc[t][n] = dbl[(rowbase + t) * 80 + 48 + n];
  }
  __syncthreads();
  for (int tj = 0; tj < TC; ++tj) {
    long off = (rowbase + tj) * D_INNER + d;
    float dtv = dt[off];
    float xv = xy[off];
    float zv = z[off];
    float dtx = dtv * xv;
    float y = 0.f;
    #pragma unroll
    for (int n = 0; n < D_STATE; ++n) {
      float dA = __expf(dtv * Arow[n]);
      h[n] = fmaf(h[n], dA, dtx * bc[tj][n]);
      y = fmaf(h[n], bc[tj][16 + n], y);
    }
    y = fmaf(xv, Dd, y);
    y *= siluf(zv);
    xy[off] = y;
  }
}

extern "C" void kernel_launch(void* const* d_in, const int* in_sizes, int n_in,
                              void* d_out, int out_size, void* d_ws, size_t ws_size,
                              hipStream_t stream) {
  const float* h        = (const float*)d_in[0];
  const float* in_proj[2] = {(const float*)d_in[1], (const float*)d_in[10]};
  const float* conv_w[2]  = {(const float*)d_in[2], (const float*)d_in[11]};
  const float* conv_b[2]  = {(const float*)d_in[3], (const float*)d_in[12]};
  const float* xproj[2]   = {(const float*)d_in[4], (const float*)d_in[13]};
  const float* dtw[2]     = {(const float*)d_in[5], (const float*)d_in[14]};
  const float* dtb[2]     = {(const float*)d_in[6], (const float*)d_in[15]};
  const float* A_log[2]   = {(const float*)d_in[7], (const float*)d_in[16]};
  const float* Dsk[2]     = {(const float*)d_in[8], (const float*)d_in[17]};
  const float* outp[2]    = {(const float*)d_in[9], (const float*)d_in[18]};
  float* out = (float*)d_out;
  float* ws = (float*)d_ws;

  const long S1 = (long)B_SZ * L_SEQ * D_INNER;
  float* xpre  = ws;            // [2][4096][1536]  (becomes dt)
  float* zbuf  = ws + 2 * S1;
  float* xconv = ws + 4 * S1;   // x, then y in-place
  float* dbl   = ws + 6 * S1;   // [2][4096][80]
  float* stS   = dbl + 2L * B_SZ * L_SEQ * 80;   // [2][2][NC][D][16]; doubles as xproj partial
  float* stP   = stS + 2L * B_SZ * NC * D_INNER * D_STATE;
  float* partial = stS;         // 2*NSPL*4096*80 = 2.6M floats < 3.1M (stS) — phase-disjoint

  dim3 blk(256);
  const int M = B_SZ * L_SEQ;   // 4096

  // 1. in_proj (MFMA 3xbf16) -> x (pre-conv) and z
  {
    dim3 grid((2 * D_INNER) / 128, M / 128);
    gemm_mfma<1, 0, 0><<<grid, blk, 0, stream>>>(h, D_MODEL, in_proj[0],
        xpre, zbuf, D_INNER, M, 2 * D_INNER, D_MODEL);
    gemm_mfma<1, 1, 0><<<grid, blk, 0, stream>>>(h, D_MODEL, in_proj[1],
        xpre + S1, zbuf + S1, D_INNER, M, 2 * D_INNER, D_MODEL);
  }
  // 2. conv + silu
  {
    long total = 2 * S1;
    conv_silu<<<dim3((unsigned)((total + 255) / 256)), blk, 0, stream>>>(
        xpre, conv_w[0], conv_b[0], conv_w[1], conv_b[1], xconv);
  }
  // 3. xproj (split-K) -> dbl
  {
    dim3 grid(M / 64, NSPL, 2);
    xproj_splitk<<<grid, blk, 0, stream>>>(xconv, xproj[0], xproj[1], partial);
    long n = 2L * M * 80;
    xproj_reduce<<<dim3((unsigned)(n / 256)), blk, 0, stream>>>(partial, dbl);
  }
  // 4. dtproj + bias + softplus -> dt
  for (int dir = 0; dir < 2; ++dir) {
    dim3 grid(D_INNER / 128, M / 128);
    gemm128<2><<<grid, blk, 0, stream>>>(dbl + (long)dir * M * 80, 80,
        dtw[dir], dtb[dir], xpre + dir * S1, D_INNER, M, D_INNER, DT_RANK);
  }
  // 5. chunked scan
  {
    dim3 grid1(NC * NDG, B_SZ, 2);
    scan_part1<<<grid1, blk, 0, stream>>>(xpre, xconv, dbl,
        A_log[0], A_log[1], stS, stP);
    long nfix = 2L * B_SZ * D_INNER * D_STATE;
    scan_fix<<<dim3((unsigned)(nfix / 256)), blk, 0, stream>>>(stS, stP);
    scan_part2<<<grid1, blk, 0, stream>>>(xpre, xconv, dbl, zbuf,
        A_log[0], A_log[1], Dsk[0], Dsk[1], stS);
  }
  // 6. out_proj (MFMA 3xbf16): fwd assign, rev add with reversed rows
  {
    dim3 grid(D_MODEL / 128, M / 128);
    gemm_mfma<0, 0, 0><<<grid, blk, 0, stream>>>(xconv, D_INNER, outp[0],
        out, nullptr, D_MODEL, M, D_MODEL, D_INNER);
    gemm_mfma<3, 0, 1><<<grid, blk, 0, stream>>>(xconv + S1, D_INNER, outp[1],
        out, nullptr, D_MODEL, M, D_MODEL, D_INNER);
  }
}

// Round 4
// 587.891 us; speedup vs baseline: 5.9025x; 1.1627x over previous
//
#include <hip/hip_runtime.h>
#include <hip/hip_bf16.h>
#include <math.h>

#define L_SEQ 2048
#define B_SZ 2
#define D_MODEL 768
#define D_INNER 1536
#define D_STATE 16
#define DT_RANK 48
#define TC 64
#define NC (L_SEQ / TC)          // 32 chunks
#define NDG (D_INNER / 256)      // 6 d-groups
#define NSPL 4
#define KCH (D_INNER / NSPL)     // 384

typedef short bf16x8 __attribute__((ext_vector_type(8)));
typedef float f32x4 __attribute__((ext_vector_type(4)));

#define GLOAD16(g, l) __builtin_amdgcn_global_load_lds( \
    (const __attribute__((address_space(1))) unsigned*)(g), \
    (__attribute__((address_space(3))) unsigned*)(l), 16, 0, 0)

static __device__ __forceinline__ float siluf(float v) {
  return v / (1.0f + __expf(-v));
}
static __device__ __forceinline__ float softplusf(float v) {
  return fmaxf(v, 0.0f) + log1pf(__expf(-fabsf(v)));
}
static __device__ __forceinline__ unsigned short f2bf_rn(float v) {
  unsigned u = __float_as_uint(v);
  u = (u + 0x7fff + ((u >> 16) & 1)) >> 16;
  return (unsigned short)u;
}

// -------- fp32 -> bf16 hi/lo plane conversion (vectorized x4) --------------
__global__ __launch_bounds__(256) void cvt_hilo(
    const float* __restrict__ src, unsigned short* __restrict__ dh,
    unsigned short* __restrict__ dl, int n4)
{
  int i = blockIdx.x * 256 + threadIdx.x;
  if (i >= n4) return;
  float4 v = ((const float4*)src)[i];
  float vv[4] = {v.x, v.y, v.z, v.w};
  unsigned short h4[4], l4[4];
  #pragma unroll
  for (int e = 0; e < 4; ++e) {
    unsigned short hv = f2bf_rn(vv[e]);
    h4[e] = hv;
    l4[e] = f2bf_rn(vv[e] - __uint_as_float((unsigned)hv << 16));
  }
  uint2 ph, pl;
  ph.x = (unsigned)h4[0] | ((unsigned)h4[1] << 16);
  ph.y = (unsigned)h4[2] | ((unsigned)h4[3] << 16);
  pl.x = (unsigned)l4[0] | ((unsigned)l4[1] << 16);
  pl.y = (unsigned)l4[2] | ((unsigned)l4[3] << 16);
  *(uint2*)&dh[(long)i * 4] = ph;
  *(uint2*)&dl[(long)i * 4] = pl;
}

// -------- in_proj: bf16-plane MFMA GEMM, global_load_lds staging ----------
// grid: 1536 blocks 1D (24 n-tiles x 32 m-tiles x 2 dirs), XCD-swizzled.
__global__ __launch_bounds__(256) void gemm_inproj(
    const unsigned short* __restrict__ hh, const unsigned short* __restrict__ hl,
    const unsigned short* __restrict__ w0h, const unsigned short* __restrict__ w0l,
    const unsigned short* __restrict__ w1h, const unsigned short* __restrict__ w1l,
    float* __restrict__ xpre, float* __restrict__ zbuf)
{
  __shared__ unsigned short Ah[128 * 32], Al[128 * 32];
  __shared__ unsigned short Wh[128 * 32], Wl[128 * 32];
  const long S1 = (long)B_SZ * L_SEQ * D_INNER;
  const int tid = threadIdx.x;
  const int lane = tid & 63, w = tid >> 6;
  int bid = blockIdx.x;
  int swz = (bid & 7) * 192 + (bid >> 3);
  int dir = swz / 768;
  int rem = swz - dir * 768;
  int mb = rem / 24, nb = rem - (rem / 24) * 24;
  const int m0 = mb * 128, n0 = nb * 128;
  const unsigned short* Whp = dir ? w1h : w0h;
  const unsigned short* Wlp = dir ? w1l : w0l;
  const int ksl = (lane & 3) ^ ((lane >> 3) & 3);
  long aoff[2], woff[2];
  int ldsc[2];
  #pragma unroll
  for (int qq = 0; qq < 2; ++qq) {
    int cq = w * 2 + qq;
    int r = cq * 16 + (lane >> 2);
    int mr = m0 + r;
    int row = dir ? ((mr & ~(L_SEQ - 1)) | ((L_SEQ - 1) - (mr & (L_SEQ - 1)))) : mr;
    aoff[qq] = (long)row * D_MODEL + 8 * ksl;
    woff[qq] = (long)(n0 + r) * D_MODEL + 8 * ksl;
    ldsc[qq] = cq * 512;
  }
  f32x4 acc[4][4];
  #pragma unroll
  for (int i = 0; i < 4; ++i)
    #pragma unroll
    for (int j = 0; j < 4; ++j) acc[i][j] = (f32x4){0.f, 0.f, 0.f, 0.f};
  const int fr = lane & 15, sl = lane >> 4;
  const int wr = w >> 1, wc = w & 1;
  int roffA[4], roffW[4];
  #pragma unroll
  for (int f = 0; f < 4; ++f) {
    int rA = wr * 64 + f * 16 + fr;
    roffA[f] = rA * 32 + ((sl ^ ((rA >> 1) & 3)) * 8);
    int rW = wc * 64 + f * 16 + fr;
    roffW[f] = rW * 32 + ((sl ^ ((rW >> 1) & 3)) * 8);
  }
  for (int k0 = 0; k0 < D_MODEL; k0 += 32) {
    __syncthreads();
    #pragma unroll
    for (int qq = 0; qq < 2; ++qq) {
      GLOAD16(hh + aoff[qq] + k0, &Ah[ldsc[qq]]);
      GLOAD16(hl + aoff[qq] + k0, &Al[ldsc[qq]]);
      GLOAD16(Whp + woff[qq] + k0, &Wh[ldsc[qq]]);
      GLOAD16(Wlp + woff[qq] + k0, &Wl[ldsc[qq]]);
    }
    __syncthreads();
    bf16x8 afh[4], afl[4];
    #pragma unroll
    for (int f = 0; f < 4; ++f) {
      afh[f] = *(const bf16x8*)&Ah[roffA[f]];
      afl[f] = *(const bf16x8*)&Al[roffA[f]];
    }
    #pragma unroll
    for (int fj = 0; fj < 4; ++fj) {
      bf16x8 wfh = *(const bf16x8*)&Wh[roffW[fj]];
      bf16x8 wfl = *(const bf16x8*)&Wl[roffW[fj]];
      #pragma unroll
      for (int fi = 0; fi < 4; ++fi) {
        acc[fi][fj] = __builtin_amdgcn_mfma_f32_16x16x32_bf16(afh[fi], wfh, acc[fi][fj], 0, 0, 0);
        acc[fi][fj] = __builtin_amdgcn_mfma_f32_16x16x32_bf16(afh[fi], wfl, acc[fi][fj], 0, 0, 0);
        acc[fi][fj] = __builtin_amdgcn_mfma_f32_16x16x32_bf16(afl[fi], wfh, acc[fi][fj], 0, 0, 0);
      }
    }
  }
  float* xq = xpre + (long)dir * S1;
  float* zq = zbuf + (long)dir * S1;
  const int fcol = lane & 15, rgrp = lane >> 4;
  #pragma unroll
  for (int fi = 0; fi < 4; ++fi) {
    #pragma unroll
    for (int j = 0; j < 4; ++j) {
      int row = m0 + wr * 64 + fi * 16 + rgrp * 4 + j;
      #pragma unroll
      for (int fj = 0; fj < 4; ++fj) {
        int n = n0 + wc * 64 + fj * 16 + fcol;
        float v = acc[fi][fj][j];
        if (n < D_INNER) xq[(long)row * D_INNER + n] = v;
        else             zq[(long)row * D_INNER + (n - D_INNER)] = v;
      }
    }
  }
}

// -------- out_proj: merged fwd+rev dual-K MFMA; W from bf16 planes --------
// grid: 192 blocks (6 n-tiles x 32 m-tiles), XCD-swizzled. Single assign write.
__global__ __launch_bounds__(256) void gemm_outproj(
    const float* __restrict__ y,   // [2][B*L][D_INNER] fp32
    const unsigned short* __restrict__ wfh, const unsigned short* __restrict__ wfl,
    const unsigned short* __restrict__ wrh, const unsigned short* __restrict__ wrl,
    float* __restrict__ out)
{
  __shared__ unsigned short Ah[128 * 32], Al[128 * 32];
  __shared__ unsigned short Wh[128 * 32], Wl[128 * 32];
  const long S1 = (long)B_SZ * L_SEQ * D_INNER;
  const int tid = threadIdx.x;
  const int lane = tid & 63, w = tid >> 6;
  int bid = blockIdx.x;
  int swz = (bid & 7) * 24 + (bid >> 3);
  int mb = swz / 6, nb = swz - (swz / 6) * 6;
  const int m0 = mb * 128, n0 = nb * 128;
  // A staging (register convert)
  const int srow = tid >> 1, sk = (tid & 1) * 16;
  const int swzA = (srow >> 1) & 3;
  // W staging (global_load_lds from planes)
  const int ksl = (lane & 3) ^ ((lane >> 3) & 3);
  long woff[2];
  int ldsc[2];
  #pragma unroll
  for (int qq = 0; qq < 2; ++qq) {
    int cq = w * 2 + qq;
    int r = cq * 16 + (lane >> 2);
    woff[qq] = (long)(n0 + r) * D_INNER + 8 * ksl;
    ldsc[qq] = cq * 512;
  }
  f32x4 acc[4][4];
  #pragma unroll
  for (int i = 0; i < 4; ++i)
    #pragma unroll
    for (int j = 0; j < 4; ++j) acc[i][j] = (f32x4){0.f, 0.f, 0.f, 0.f};
  const int fr = lane & 15, sl = lane >> 4;
  const int wr = w >> 1, wc = w & 1;
  int roffA[4], roffW[4];
  #pragma unroll
  for (int f = 0; f < 4; ++f) {
    int rA = wr * 64 + f * 16 + fr;
    roffA[f] = rA * 32 + ((sl ^ ((rA >> 1) & 3)) * 8);
    int rW = wc * 64 + f * 16 + fr;
    roffW[f] = rW * 32 + ((sl ^ ((rW >> 1) & 3)) * 8);
  }
  for (int dd = 0; dd < 2; ++dd) {
    int mr = m0 + srow;
    int rowA = dd ? ((mr & ~(L_SEQ - 1)) | ((L_SEQ - 1) - (mr & (L_SEQ - 1)))) : mr;
    const float* Aptr = y + (long)dd * S1 + (long)rowA * D_INNER + sk;
    const unsigned short* WhP = dd ? wrh : wfh;
    const unsigned short* WlP = dd ? wrl : wfl;
    for (int k0 = 0; k0 < D_INNER; k0 += 32) {
      float4 av[4];
      #pragma unroll
      for (int q = 0; q < 4; ++q) av[q] = *(const float4*)(Aptr + k0 + q * 4);
      unsigned short ah[16], al[16];
      #pragma unroll
      for (int q = 0; q < 4; ++q) {
        float va[4] = {av[q].x, av[q].y, av[q].z, av[q].w};
        #pragma unroll
        for (int e = 0; e < 4; ++e) {
          int i = q * 4 + e;
          unsigned short hv = f2bf_rn(va[e]);
          ah[i] = hv;
          al[i] = f2bf_rn(va[e] - __uint_as_float((unsigned)hv << 16));
        }
      }
      __syncthreads();   // prev iter frag reads done
      #pragma unroll
      for (int qq = 0; qq < 2; ++qq) {
        GLOAD16(WhP + woff[qq] + k0, &Wh[ldsc[qq]]);
        GLOAD16(WlP + woff[qq] + k0, &Wl[ldsc[qq]]);
      }
      #pragma unroll
      for (int s = 0; s < 2; ++s) {
        int slot = (sk >> 3) + s;
        int off = srow * 32 + ((slot ^ swzA) * 8);
        *(bf16x8*)&Ah[off] = *(const bf16x8*)&ah[s * 8];
        *(bf16x8*)&Al[off] = *(const bf16x8*)&al[s * 8];
      }
      __syncthreads();
      bf16x8 afh[4], afl[4];
      #pragma unroll
      for (int f = 0; f < 4; ++f) {
        afh[f] = *(const bf16x8*)&Ah[roffA[f]];
        afl[f] = *(const bf16x8*)&Al[roffA[f]];
      }
      #pragma unroll
      for (int fj = 0; fj < 4; ++fj) {
        bf16x8 wh = *(const bf16x8*)&Wh[roffW[fj]];
        bf16x8 wl = *(const bf16x8*)&Wl[roffW[fj]];
        #pragma unroll
        for (int fi = 0; fi < 4; ++fi) {
          acc[fi][fj] = __builtin_amdgcn_mfma_f32_16x16x32_bf16(afh[fi], wh, acc[fi][fj], 0, 0, 0);
          acc[fi][fj] = __builtin_amdgcn_mfma_f32_16x16x32_bf16(afh[fi], wl, acc[fi][fj], 0, 0, 0);
          acc[fi][fj] = __builtin_amdgcn_mfma_f32_16x16x32_bf16(afl[fi], wh, acc[fi][fj], 0, 0, 0);
        }
      }
    }
  }
  const int fcol = lane & 15, rgrp = lane >> 4;
  #pragma unroll
  for (int fi = 0; fi < 4; ++fi) {
    #pragma unroll
    for (int j = 0; j < 4; ++j) {
      int row = m0 + wr * 64 + fi * 16 + rgrp * 4 + j;
      #pragma unroll
      for (int fj = 0; fj < 4; ++fj) {
        int n = n0 + wc * 64 + fj * 16 + fcol;
        out[(long)row * D_MODEL + n] = acc[fi][fj][j];
      }
    }
  }
}

// ---------------- 128x128 fp32 VALU GEMM (dtproj only: K=48) --------------
template<int MODE>
__global__ __launch_bounds__(256) void gemm128(
    const float* __restrict__ A, int lda,
    const float* __restrict__ W,
    const float* __restrict__ bias,
    float* __restrict__ C0, int ldc,
    int M, int N, int K)
{
  __shared__ float As[16][132];
  __shared__ float Ws[16][132];
  const int tid = threadIdx.x;
  const int m0 = blockIdx.y * 128, n0 = blockIdx.x * 128;
  const int tx = tid & 15, ty = tid >> 4;
  const int lm = tid >> 1;
  const int lk = (tid & 1) * 8;
  const float* Aptr = A + (long)(m0 + lm) * lda + lk;
  const float* Wptr = W + (long)(n0 + lm) * K + lk;
  float acc[8][8] = {};
  for (int k0 = 0; k0 < K; k0 += 16) {
    float4 a0 = *(const float4*)(Aptr + k0);
    float4 a1 = *(const float4*)(Aptr + k0 + 4);
    float4 w0 = *(const float4*)(Wptr + k0);
    float4 w1 = *(const float4*)(Wptr + k0 + 4);
    As[lk + 0][lm] = a0.x; As[lk + 1][lm] = a0.y; As[lk + 2][lm] = a0.z; As[lk + 3][lm] = a0.w;
    As[lk + 4][lm] = a1.x; As[lk + 5][lm] = a1.y; As[lk + 6][lm] = a1.z; As[lk + 7][lm] = a1.w;
    Ws[lk + 0][lm] = w0.x; Ws[lk + 1][lm] = w0.y; Ws[lk + 2][lm] = w0.z; Ws[lk + 3][lm] = w0.w;
    Ws[lk + 4][lm] = w1.x; Ws[lk + 5][lm] = w1.y; Ws[lk + 6][lm] = w1.z; Ws[lk + 7][lm] = w1.w;
    __syncthreads();
    #pragma unroll
    for (int kk = 0; kk < 16; ++kk) {
      float4 av0 = *(const float4*)&As[kk][ty * 4];
      float4 av1 = *(const float4*)&As[kk][64 + ty * 4];
      float4 bv0 = *(const float4*)&Ws[kk][tx * 4];
      float4 bv1 = *(const float4*)&Ws[kk][64 + tx * 4];
      float am[8] = {av0.x, av0.y, av0.z, av0.w, av1.x, av1.y, av1.z, av1.w};
      float bn[8] = {bv0.x, bv0.y, bv0.z, bv0.w, bv1.x, bv1.y, bv1.z, bv1.w};
      #pragma unroll
      for (int i = 0; i < 8; ++i)
        #pragma unroll
        for (int j = 0; j < 8; ++j) acc[i][j] = fmaf(am[i], bn[j], acc[i][j]);
    }
    __syncthreads();
  }
  #pragma unroll
  for (int i = 0; i < 8; ++i) {
    int row = m0 + ty * 4 + (i & 3) + ((i >> 2) << 6);
    #pragma unroll
    for (int j = 0; j < 8; ++j) {
      int n = n0 + tx * 4 + (j & 3) + ((j >> 2) << 6);
      float v = acc[i][j];
      if (MODE == 2) { v += bias[n]; v = softplusf(v); }
      C0[(long)row * ldc + n] = v;
    }
  }
}

// ---------------- xproj: split-K tall-skinny GEMM (N=80) ------------------
__global__ __launch_bounds__(256) void xproj_splitk(
    const float* __restrict__ X,
    const float* __restrict__ xproj_f, const float* __restrict__ xproj_r,
    float* __restrict__ partial)
{
  const int tid = threadIdx.x;
  const int m0 = blockIdx.x * 64;
  const int kz = blockIdx.y;
  const int dir = blockIdx.z;
  const float* W = dir ? xproj_r : xproj_f;
  const float* A = X + (long)dir * B_SZ * L_SEQ * D_INNER;
  __shared__ float As[16][65];
  __shared__ float Ws[16][81];
  const int lk = tid & 15, lr = tid >> 4;
  const int tx = tid & 15, ty = tid >> 4;
  float acc[4][5] = {};
  const int kbase = kz * KCH;
  for (int k0 = 0; k0 < KCH; k0 += 16) {
    #pragma unroll
    for (int i = 0; i < 4; ++i)
      As[lk][lr + 16 * i] = A[(long)(m0 + lr + 16 * i) * D_INNER + kbase + k0 + lk];
    for (int r = lr; r < 80; r += 16)
      Ws[lk][r] = W[(long)r * D_INNER + kbase + k0 + lk];
    __syncthreads();
    #pragma unroll
    for (int kk = 0; kk < 16; ++kk) {
      float a[4], b[5];
      #pragma unroll
      for (int i = 0; i < 4; ++i) a[i] = As[kk][ty + 16 * i];
      #pragma unroll
      for (int j = 0; j < 5; ++j) b[j] = Ws[kk][tx * 5 + j];
      #pragma unroll
      for (int i = 0; i < 4; ++i)
        #pragma unroll
        for (int j = 0; j < 5; ++j) acc[i][j] = fmaf(a[i], b[j], acc[i][j]);
    }
    __syncthreads();
  }
  float* P = partial + (((long)dir * NSPL + kz) * (B_SZ * L_SEQ) + m0) * 80;
  #pragma unroll
  for (int i = 0; i < 4; ++i)
    #pragma unroll
    for (int j = 0; j < 5; ++j)
      P[(long)(ty + 16 * i) * 80 + tx * 5 + j] = acc[i][j];
}

__global__ __launch_bounds__(256) void xproj_reduce(
    const float* __restrict__ partial, float* __restrict__ dbl)
{
  long idx = (long)blockIdx.x * 256 + threadIdx.x;
  const long plane = (long)B_SZ * L_SEQ * 80;
  long dir = idx / plane;
  long rc = idx % plane;
  const float* P = partial + dir * NSPL * plane + rc;
  float s = 0.f;
  #pragma unroll
  for (int z = 0; z < NSPL; ++z) s += P[z * plane];
  dbl[idx] = s;
}

// -------- causal depthwise conv (w=4) + bias + silu, float4 ---------------
__global__ __launch_bounds__(256) void conv_silu_v4(
    const float* __restrict__ xpre,
    const float* __restrict__ w_f, const float* __restrict__ b_f,
    const float* __restrict__ w_r, const float* __restrict__ b_r,
    float* __restrict__ xconv)
{
  long i4 = (long)blockIdx.x * 256 + threadIdx.x;
  const long total4 = 2L * B_SZ * L_SEQ * D_INNER / 4;
  if (i4 >= total4) return;
  long idx = i4 * 4;
  int d0 = (int)(idx % D_INNER);
  long r = idx / D_INNER;
  int t = (int)(r & (L_SEQ - 1));
  int dir = (int)(r >> 12);
  const float* w  = dir ? w_r : w_f;
  const float* cb = dir ? b_r : b_f;
  float4 a = *(const float4*)&cb[d0];
  float4 wc[4];
  #pragma unroll
  for (int i = 0; i < 4; ++i) wc[i] = *(const float4*)&w[(d0 + i) * 4];
  #pragma unroll
  for (int k = 0; k < 4; ++k) {
    if (t - 3 + k >= 0) {
      float4 xv = *(const float4*)&xpre[(r - 3 + k) * D_INNER + d0];
      a.x = fmaf(((const float*)&wc[0])[k], xv.x, a.x);
      a.y = fmaf(((const float*)&wc[1])[k], xv.y, a.y);
      a.z = fmaf(((const float*)&wc[2])[k], xv.z, a.z);
      a.w = fmaf(((const float*)&wc[3])[k], xv.w, a.w);
    }
  }
  a.x = siluf(a.x); a.y = siluf(a.y); a.z = siluf(a.z); a.w = siluf(a.w);
  *(float4*)&xconv[idx] = a;
}

// ---------------- chunked selective scan ----------------
__global__ __launch_bounds__(256) void scan_part1(
    const float* __restrict__ dt, const float* __restrict__ x,
    const float* __restrict__ dbl,
    const float* __restrict__ A_log_f, const float* __restrict__ A_log_r,
    float* __restrict__ stateS, float* __restrict__ stateP)
{
  const int tid = threadIdx.x;
  const int chunk = blockIdx.x / NDG;
  const int d = (blockIdx.x % NDG) * 256 + tid;
  const int b = blockIdx.y, dir = blockIdx.z;
  const float* A_log = dir ? A_log_r : A_log_f;
  float Arow[D_STATE];
  #pragma unroll
  for (int n = 0; n < D_STATE; ++n) Arow[n] = -expf(A_log[d * D_STATE + n]);
  float h[D_STATE], P[D_STATE];
  #pragma unroll
  for (int n = 0; n < D_STATE; ++n) { h[n] = 0.f; P[n] = 1.f; }
  const long rowbase = ((long)dir * B_SZ + b) * L_SEQ + (long)chunk * TC;
  __shared__ float bt[TC][D_STATE];
  for (int i = tid; i < TC * D_STATE; i += 256) {
    int t = i >> 4, n = i & 15;
    bt[t][n] = dbl[(rowbase + t) * 80 + 48 + n];
  }
  __syncthreads();
  for (int tj = 0; tj < TC; ++tj) {
    long off = (rowbase + tj) * D_INNER + d;
    float dtv = dt[off];
    float xv = x[off];
    float dtx = dtv * xv;
    #pragma unroll
    for (int n = 0; n < D_STATE; ++n) {
      float dA = __expf(dtv * Arow[n]);
      P[n] *= dA;
      h[n] = fmaf(h[n], dA, dtx * bt[tj][n]);
    }
  }
  long base = ((((long)dir * B_SZ + b) * NC + chunk) * D_INNER + d) * D_STATE;
  #pragma unroll
  for (int n = 0; n < D_STATE; ++n) { stateS[base + n] = h[n]; stateP[base + n] = P[n]; }
}

__global__ __launch_bounds__(256) void scan_fix(
    float* __restrict__ stateS, const float* __restrict__ stateP)
{
  const long idx = (long)blockIdx.x * 256 + threadIdx.x;
  const int DN = D_INNER * D_STATE;
  const long dirb = idx / DN;
  const int dn = (int)(idx % DN);
  long base = dirb * NC * DN + dn;
  float h = 0.f;
  for (int c = 0; c < NC; ++c) {
    long o = base + (long)c * DN;
    float S = stateS[o];
    float Pc = stateP[o];
    stateS[o] = h;
    h = fmaf(h, Pc, S);
  }
}

__global__ __launch_bounds__(256) void scan_part2(
    const float* __restrict__ dt, float* __restrict__ xy,
    const float* __restrict__ dbl, const float* __restrict__ z,
    const float* __restrict__ A_log_f, const float* __restrict__ A_log_r,
    const float* __restrict__ Ds_f, const float* __restrict__ Ds_r,
    const float* __restrict__ stateS)
{
  const int tid = threadIdx.x;
  const int chunk = blockIdx.x / NDG;
  const int d = (blockIdx.x % NDG) * 256 + tid;
  const int b = blockIdx.y, dir = blockIdx.z;
  const float* A_log = dir ? A_log_r : A_log_f;
  const float* Ds = dir ? Ds_r : Ds_f;
  float Arow[D_STATE];
  #pragma unroll
  for (int n = 0; n < D_STATE; ++n) Arow[n] = -expf(A_log[d * D_STATE + n]);
  const float Dd = Ds[d];
  float h[D_STATE];
  long sbase = ((((long)dir * B_SZ + b) * NC + chunk) * D_INNER + d) * D_STATE;
  #pragma unroll
  for (int n = 0; n < D_STATE; ++n) h[n] = stateS[sbase + n];
  const long rowbase = ((long)dir * B_SZ + b) * L_SEQ + (long)chunk * TC;
  __shared__ float bc[TC][2 * D_STATE];
  for (int i = tid; i < TC * 2 * D_STATE; i += 256) {
    int t = i >> 5, n = i & 31;
    bc[t][n] = dbl[(rowbase + t) * 80 + 48 + n];
  }
  __syncthreads();
  for (int tj = 0; tj < TC; ++tj) {
    long off = (rowbase + tj) * D_INNER + d;
    float dtv = dt[off];
    float xv = xy[off];
    float zv = z[off];
    float dtx = dtv * xv;
    float y = 0.f;
    #pragma unroll
    for (int n = 0; n < D_STATE; ++n) {
      float dA = __expf(dtv * Arow[n]);
      h[n] = fmaf(h[n], dA, dtx * bc[tj][n]);
      y = fmaf(h[n], bc[tj][16 + n], y);
    }
    y = fmaf(xv, Dd, y);
    y *= siluf(zv);
    xy[off] = y;
  }
}

extern "C" void kernel_launch(void* const* d_in, const int* in_sizes, int n_in,
                              void* d_out, int out_size, void* d_ws, size_t ws_size,
                              hipStream_t stream) {
  const float* h        = (const float*)d_in[0];
  const float* in_proj[2] = {(const float*)d_in[1], (const float*)d_in[10]};
  const float* conv_w[2]  = {(const float*)d_in[2], (const float*)d_in[11]};
  const float* conv_b[2]  = {(const float*)d_in[3], (const float*)d_in[12]};
  const float* xproj[2]   = {(const float*)d_in[4], (const float*)d_in[13]};
  const float* dtw[2]     = {(const float*)d_in[5], (const float*)d_in[14]};
  const float* dtb[2]     = {(const float*)d_in[6], (const float*)d_in[15]};
  const float* A_log[2]   = {(const float*)d_in[7], (const float*)d_in[16]};
  const float* Dsk[2]     = {(const float*)d_in[8], (const float*)d_in[17]};
  const float* outp[2]    = {(const float*)d_in[9], (const float*)d_in[18]};
  float* out = (float*)d_out;
  float* ws = (float*)d_ws;

  const long S1 = (long)B_SZ * L_SEQ * D_INNER;   // 6,291,456
  const int M = B_SZ * L_SEQ;                     // 4096
  float* xpre  = ws;                 // [2][4096][1536]  (becomes dt)
  float* zbuf  = ws + 2 * S1;
  float* xconv = ws + 4 * S1;        // x, then y in-place
  float* dbl   = ws + 6 * S1;        // [2][4096][80]
  float* stS   = dbl + 2L * M * 80;  // [2][2][NC][D][16]
  const long SST = 2L * B_SZ * NC * D_INNER * D_STATE;  // 3,145,728
  float* stP   = stS + SST;
  float* partial = stS;              // xproj partials (phase-disjoint w/ planes & states)

  // bf16 hi/lo planes, overlapping stS/stP (+ tail past stP for out_proj W)
  unsigned short* hh  = (unsigned short*)stS;               // 3,145,728 each
  unsigned short* hl  = hh + 3145728;
  unsigned short* w0h = hl + 3145728;                       // 2,359,296 each
  unsigned short* w0l = w0h + 2359296;
  unsigned short* w1h = w0l + 2359296;
  unsigned short* w1l = w1h + 2359296;
  unsigned short* o0h = w1l + 2359296;                      // 1,179,648 each (past stP)
  unsigned short* o0l = o0h + 1179648;
  unsigned short* o1h = o0l + 1179648;
  unsigned short* o1l = o1h + 1179648;

  dim3 blk(256);

  // 0. pre-convert h + weights to bf16 hi/lo planes
  cvt_hilo<<<dim3(3145728 / 4 / 256), blk, 0, stream>>>(h, hh, hl, 3145728 / 4);
  cvt_hilo<<<dim3(2359296 / 4 / 256), blk, 0, stream>>>(in_proj[0], w0h, w0l, 2359296 / 4);
  cvt_hilo<<<dim3(2359296 / 4 / 256), blk, 0, stream>>>(in_proj[1], w1h, w1l, 2359296 / 4);
  cvt_hilo<<<dim3(1179648 / 4 / 256), blk, 0, stream>>>(outp[0], o0h, o0l, 1179648 / 4);
  cvt_hilo<<<dim3(1179648 / 4 / 256), blk, 0, stream>>>(outp[1], o1h, o1l, 1179648 / 4);

  // 1. in_proj (both dirs, one dispatch) -> x (pre-conv) and z
  gemm_inproj<<<dim3(1536), blk, 0, stream>>>(hh, hl, w0h, w0l, w1h, w1l, xpre, zbuf);

  // 2. conv + silu (float4)
  conv_silu_v4<<<dim3((unsigned)(2 * S1 / 4 / 256)), blk, 0, stream>>>(
      xpre, conv_w[0], conv_b[0], conv_w[1], conv_b[1], xconv);

  // 3. xproj (split-K) -> dbl
  {
    dim3 grid(M / 64, NSPL, 2);
    xproj_splitk<<<grid, blk, 0, stream>>>(xconv, xproj[0], xproj[1], partial);
    long n = 2L * M * 80;
    xproj_reduce<<<dim3((unsigned)(n / 256)), blk, 0, stream>>>(partial, dbl);
  }
  // 4. dtproj + bias + softplus -> dt (overwrites xpre)
  for (int dir = 0; dir < 2; ++dir) {
    dim3 grid(D_INNER / 128, M / 128);
    gemm128<2><<<grid, blk, 0, stream>>>(dbl + (long)dir * M * 80, 80,
        dtw[dir], dtb[dir], xpre + dir * S1, D_INNER, M, D_INNER, DT_RANK);
  }
  // 5. chunked scan (y in place of xconv)
  {
    dim3 grid1(NC * NDG, B_SZ, 2);
    scan_part1<<<grid1, blk, 0, stream>>>(xpre, xconv, dbl,
        A_log[0], A_log[1], stS, stP);
    long nfix = 2L * B_SZ * D_INNER * D_STATE;
    scan_fix<<<dim3((unsigned)(nfix / 256)), blk, 0, stream>>>(stS, stP);
    scan_part2<<<grid1, blk, 0, stream>>>(xpre, xconv, dbl, zbuf,
        A_log[0], A_log[1], Dsk[0], Dsk[1], stS);
  }
  // 6. out_proj: merged fwd+rev, single assign write
  gemm_outproj<<<dim3(192), blk, 0, stream>>>(xconv, o0h, o0l, o1h, o1l, out);
}

// Round 5
// 508.654 us; speedup vs baseline: 6.8220x; 1.1558x over previous
//
#include <hip/hip_runtime.h>
#include <hip/hip_bf16.h>
#include <math.h>

#define L_SEQ 2048
#define B_SZ 2
#define D_MODEL 768
#define D_INNER 1536
#define D_STATE 16
#define DT_RANK 48
#define TC 64
#define NC (L_SEQ / TC)          // 32 chunks
#define NDG (D_INNER / 256)      // 6 d-groups
#define NSPL 4
#define KCH (D_INNER / NSPL)     // 384

typedef short bf16x8 __attribute__((ext_vector_type(8)));
typedef float f32x4 __attribute__((ext_vector_type(4)));

#define GLOAD16(g, l) __builtin_amdgcn_global_load_lds( \
    (const __attribute__((address_space(1))) unsigned*)(g), \
    (__attribute__((address_space(3))) unsigned*)(l), 16, 0, 0)

static __device__ __forceinline__ float siluf(float v) {
  return v / (1.0f + __expf(-v));
}
static __device__ __forceinline__ float softplusf(float v) {
  return fmaxf(v, 0.0f) + log1pf(__expf(-fabsf(v)));
}
static __device__ __forceinline__ unsigned short f2bf_rn(float v) {
  unsigned u = __float_as_uint(v);
  u = (u + 0x7fff + ((u >> 16) & 1)) >> 16;
  return (unsigned short)u;
}

// -------- fused fp32 -> bf16 hi/lo conversion for all 5 tensors -----------
__global__ __launch_bounds__(256) void cvt_all(
    const float* __restrict__ s_h,  unsigned short* __restrict__ hh,  unsigned short* __restrict__ hl,
    const float* __restrict__ s_w0, unsigned short* __restrict__ w0h, unsigned short* __restrict__ w0l,
    const float* __restrict__ s_w1, unsigned short* __restrict__ w1h, unsigned short* __restrict__ w1l,
    const float* __restrict__ s_o0, unsigned short* __restrict__ o0h, unsigned short* __restrict__ o0l,
    const float* __restrict__ s_o1, unsigned short* __restrict__ o1h, unsigned short* __restrict__ o1l)
{
  long j = (long)blockIdx.x * 256 + threadIdx.x;   // float4 index
  const long N0 = 786432, N1 = 589824, N2 = 589824, N3 = 294912;
  const float* src; unsigned short *dh, *dl;
  if (j < N0) { src = s_h; dh = hh; dl = hl; }
  else if ((j -= N0) < N1) { src = s_w0; dh = w0h; dl = w0l; }
  else if ((j -= N1) < N2) { src = s_w1; dh = w1h; dl = w1l; }
  else if ((j -= N2) < N3) { src = s_o0; dh = o0h; dl = o0l; }
  else { j -= N3; src = s_o1; dh = o1h; dl = o1l; }
  float4 v = ((const float4*)src)[j];
  float vv[4] = {v.x, v.y, v.z, v.w};
  unsigned short h4[4], l4[4];
  #pragma unroll
  for (int e = 0; e < 4; ++e) {
    unsigned short hv = f2bf_rn(vv[e]);
    h4[e] = hv;
    l4[e] = f2bf_rn(vv[e] - __uint_as_float((unsigned)hv << 16));
  }
  uint2 ph, pl;
  ph.x = (unsigned)h4[0] | ((unsigned)h4[1] << 16);
  ph.y = (unsigned)h4[2] | ((unsigned)h4[3] << 16);
  pl.x = (unsigned)l4[0] | ((unsigned)l4[1] << 16);
  pl.y = (unsigned)l4[2] | ((unsigned)l4[3] << 16);
  *(uint2*)&dh[j * 4] = ph;
  *(uint2*)&dl[j * 4] = pl;
}

// -------- in_proj: bf16-plane MFMA GEMM, global_load_lds staging ----------
__global__ __launch_bounds__(256) void gemm_inproj(
    const unsigned short* __restrict__ hh, const unsigned short* __restrict__ hl,
    const unsigned short* __restrict__ w0h, const unsigned short* __restrict__ w0l,
    const unsigned short* __restrict__ w1h, const unsigned short* __restrict__ w1l,
    float* __restrict__ xpre, float* __restrict__ zbuf)
{
  __shared__ unsigned short Ah[128 * 32], Al[128 * 32];
  __shared__ unsigned short Wh[128 * 32], Wl[128 * 32];
  const long S1 = (long)B_SZ * L_SEQ * D_INNER;
  const int tid = threadIdx.x;
  const int lane = tid & 63, w = tid >> 6;
  int bid = blockIdx.x;
  int swz = (bid & 7) * 192 + (bid >> 3);
  int dir = swz / 768;
  int rem = swz - dir * 768;
  int mb = rem / 24, nb = rem - (rem / 24) * 24;
  const int m0 = mb * 128, n0 = nb * 128;
  const unsigned short* Whp = dir ? w1h : w0h;
  const unsigned short* Wlp = dir ? w1l : w0l;
  const int ksl = (lane & 3) ^ ((lane >> 3) & 3);
  long aoff[2], woff[2];
  int ldsc[2];
  #pragma unroll
  for (int qq = 0; qq < 2; ++qq) {
    int cq = w * 2 + qq;
    int r = cq * 16 + (lane >> 2);
    int mr = m0 + r;
    int row = dir ? ((mr & ~(L_SEQ - 1)) | ((L_SEQ - 1) - (mr & (L_SEQ - 1)))) : mr;
    aoff[qq] = (long)row * D_MODEL + 8 * ksl;
    woff[qq] = (long)(n0 + r) * D_MODEL + 8 * ksl;
    ldsc[qq] = cq * 512;
  }
  f32x4 acc[4][4];
  #pragma unroll
  for (int i = 0; i < 4; ++i)
    #pragma unroll
    for (int j = 0; j < 4; ++j) acc[i][j] = (f32x4){0.f, 0.f, 0.f, 0.f};
  const int fr = lane & 15, sl = lane >> 4;
  const int wr = w >> 1, wc = w & 1;
  int roffA[4], roffW[4];
  #pragma unroll
  for (int f = 0; f < 4; ++f) {
    int rA = wr * 64 + f * 16 + fr;
    roffA[f] = rA * 32 + ((sl ^ ((rA >> 1) & 3)) * 8);
    int rW = wc * 64 + f * 16 + fr;
    roffW[f] = rW * 32 + ((sl ^ ((rW >> 1) & 3)) * 8);
  }
  for (int k0 = 0; k0 < D_MODEL; k0 += 32) {
    __syncthreads();
    #pragma unroll
    for (int qq = 0; qq < 2; ++qq) {
      GLOAD16(hh + aoff[qq] + k0, &Ah[ldsc[qq]]);
      GLOAD16(hl + aoff[qq] + k0, &Al[ldsc[qq]]);
      GLOAD16(Whp + woff[qq] + k0, &Wh[ldsc[qq]]);
      GLOAD16(Wlp + woff[qq] + k0, &Wl[ldsc[qq]]);
    }
    __syncthreads();
    bf16x8 afh[4], afl[4];
    #pragma unroll
    for (int f = 0; f < 4; ++f) {
      afh[f] = *(const bf16x8*)&Ah[roffA[f]];
      afl[f] = *(const bf16x8*)&Al[roffA[f]];
    }
    #pragma unroll
    for (int fj = 0; fj < 4; ++fj) {
      bf16x8 wfh = *(const bf16x8*)&Wh[roffW[fj]];
      bf16x8 wfl = *(const bf16x8*)&Wl[roffW[fj]];
      #pragma unroll
      for (int fi = 0; fi < 4; ++fi) {
        acc[fi][fj] = __builtin_amdgcn_mfma_f32_16x16x32_bf16(afh[fi], wfh, acc[fi][fj], 0, 0, 0);
        acc[fi][fj] = __builtin_amdgcn_mfma_f32_16x16x32_bf16(afh[fi], wfl, acc[fi][fj], 0, 0, 0);
        acc[fi][fj] = __builtin_amdgcn_mfma_f32_16x16x32_bf16(afl[fi], wfh, acc[fi][fj], 0, 0, 0);
      }
    }
  }
  float* xq = xpre + (long)dir * S1;
  float* zq = zbuf + (long)dir * S1;
  const int fcol = lane & 15, rgrp = lane >> 4;
  #pragma unroll
  for (int fi = 0; fi < 4; ++fi) {
    #pragma unroll
    for (int j = 0; j < 4; ++j) {
      int row = m0 + wr * 64 + fi * 16 + rgrp * 4 + j;
      #pragma unroll
      for (int fj = 0; fj < 4; ++fj) {
        int n = n0 + wc * 64 + fj * 16 + fcol;
        float v = acc[fi][fj][j];
        if (n < D_INNER) xq[(long)row * D_INNER + n] = v;
        else             zq[(long)row * D_INNER + (n - D_INNER)] = v;
      }
    }
  }
}

// -------- out_proj: split-(dir,K) MFMA; partials, A converted in-regs -----
// grid: 768 blocks = 2 dir x 2 ks x 32 mb x 6 nb, XCD-swizzled.
__global__ __launch_bounds__(256) void gemm_outproj_sk(
    const float* __restrict__ y,   // [2][B*L][D_INNER] fp32
    const unsigned short* __restrict__ wfh, const unsigned short* __restrict__ wfl,
    const unsigned short* __restrict__ wrh, const unsigned short* __restrict__ wrl,
    float* __restrict__ partial)   // [4][4096][768], plane = dir*2+ks
{
  __shared__ unsigned short Ah[128 * 32], Al[128 * 32];
  __shared__ unsigned short Wh[128 * 32], Wl[128 * 32];
  const long S1 = (long)B_SZ * L_SEQ * D_INNER;
  const int tid = threadIdx.x;
  const int lane = tid & 63, w = tid >> 6;
  int bid = blockIdx.x;
  int swz = (bid & 7) * 96 + (bid >> 3);
  int dir = swz / 384;
  int r1 = swz - dir * 384;
  int ks = r1 / 192;
  int r2 = r1 - ks * 192;
  int mb = r2 / 6, nb = r2 - (r2 / 6) * 6;
  const int m0 = mb * 128, n0 = nb * 128;
  const int kbase = ks * (D_INNER / 2);
  // A staging (register convert)
  const int srow = tid >> 1, sk = (tid & 1) * 16;
  const int swzA = (srow >> 1) & 3;
  {
  }
  int mr = m0 + srow;
  int rowA = dir ? ((mr & ~(L_SEQ - 1)) | ((L_SEQ - 1) - (mr & (L_SEQ - 1)))) : mr;
  const float* Aptr = y + (long)dir * S1 + (long)rowA * D_INNER + sk;
  // W staging (global_load_lds from planes)
  const unsigned short* WhP = dir ? wrh : wfh;
  const unsigned short* WlP = dir ? wrl : wfl;
  const int ksl = (lane & 3) ^ ((lane >> 3) & 3);
  long woff[2];
  int ldsc[2];
  #pragma unroll
  for (int qq = 0; qq < 2; ++qq) {
    int cq = w * 2 + qq;
    int r = cq * 16 + (lane >> 2);
    woff[qq] = (long)(n0 + r) * D_INNER + 8 * ksl;
    ldsc[qq] = cq * 512;
  }
  f32x4 acc[4][4];
  #pragma unroll
  for (int i = 0; i < 4; ++i)
    #pragma unroll
    for (int j = 0; j < 4; ++j) acc[i][j] = (f32x4){0.f, 0.f, 0.f, 0.f};
  const int fr = lane & 15, sl = lane >> 4;
  const int wr = w >> 1, wc = w & 1;
  int roffA[4], roffW[4];
  #pragma unroll
  for (int f = 0; f < 4; ++f) {
    int rA = wr * 64 + f * 16 + fr;
    roffA[f] = rA * 32 + ((sl ^ ((rA >> 1) & 3)) * 8);
    int rW = wc * 64 + f * 16 + fr;
    roffW[f] = rW * 32 + ((sl ^ ((rW >> 1) & 3)) * 8);
  }
  for (int k0 = kbase; k0 < kbase + D_INNER / 2; k0 += 32) {
    float4 av[4];
    #pragma unroll
    for (int q = 0; q < 4; ++q) av[q] = *(const float4*)(Aptr + k0 + q * 4);
    unsigned short ah[16], al[16];
    #pragma unroll
    for (int q = 0; q < 4; ++q) {
      float va[4] = {av[q].x, av[q].y, av[q].z, av[q].w};
      #pragma unroll
      for (int e = 0; e < 4; ++e) {
        int i = q * 4 + e;
        unsigned short hv = f2bf_rn(va[e]);
        ah[i] = hv;
        al[i] = f2bf_rn(va[e] - __uint_as_float((unsigned)hv << 16));
      }
    }
    __syncthreads();   // prev iter frag reads done
    #pragma unroll
    for (int qq = 0; qq < 2; ++qq) {
      GLOAD16(WhP + woff[qq] + k0, &Wh[ldsc[qq]]);
      GLOAD16(WlP + woff[qq] + k0, &Wl[ldsc[qq]]);
    }
    #pragma unroll
    for (int s = 0; s < 2; ++s) {
      int slot = (sk >> 3) + s;
      int off = srow * 32 + ((slot ^ swzA) * 8);
      *(bf16x8*)&Ah[off] = *(const bf16x8*)&ah[s * 8];
      *(bf16x8*)&Al[off] = *(const bf16x8*)&al[s * 8];
    }
    __syncthreads();
    bf16x8 afh[4], afl[4];
    #pragma unroll
    for (int f = 0; f < 4; ++f) {
      afh[f] = *(const bf16x8*)&Ah[roffA[f]];
      afl[f] = *(const bf16x8*)&Al[roffA[f]];
    }
    #pragma unroll
    for (int fj = 0; fj < 4; ++fj) {
      bf16x8 wh = *(const bf16x8*)&Wh[roffW[fj]];
      bf16x8 wl = *(const bf16x8*)&Wl[roffW[fj]];
      #pragma unroll
      for (int fi = 0; fi < 4; ++fi) {
        acc[fi][fj] = __builtin_amdgcn_mfma_f32_16x16x32_bf16(afh[fi], wh, acc[fi][fj], 0, 0, 0);
        acc[fi][fj] = __builtin_amdgcn_mfma_f32_16x16x32_bf16(afh[fi], wl, acc[fi][fj], 0, 0, 0);
        acc[fi][fj] = __builtin_amdgcn_mfma_f32_16x16x32_bf16(afl[fi], wh, acc[fi][fj], 0, 0, 0);
      }
    }
  }
  float* P = partial + (long)(dir * 2 + ks) * (B_SZ * L_SEQ) * D_MODEL;
  const int fcol = lane & 15, rgrp = lane >> 4;
  #pragma unroll
  for (int fi = 0; fi < 4; ++fi) {
    #pragma unroll
    for (int j = 0; j < 4; ++j) {
      int row = m0 + wr * 64 + fi * 16 + rgrp * 4 + j;
      #pragma unroll
      for (int fj = 0; fj < 4; ++fj) {
        int n = n0 + wc * 64 + fj * 16 + fcol;
        P[(long)row * D_MODEL + n] = acc[fi][fj][j];
      }
    }
  }
}

__global__ __launch_bounds__(256) void outproj_reduce(
    const float* __restrict__ partial, float* __restrict__ out)
{
  long i = (long)blockIdx.x * 256 + threadIdx.x;   // float4 index
  const long plane4 = (long)B_SZ * L_SEQ * D_MODEL / 4;  // 786432
  float4 a = ((const float4*)partial)[i];
  float4 b = ((const float4*)partial)[i + plane4];
  float4 c = ((const float4*)partial)[i + 2 * plane4];
  float4 d = ((const float4*)partial)[i + 3 * plane4];
  float4 s;
  s.x = (a.x + b.x) + (c.x + d.x);
  s.y = (a.y + b.y) + (c.y + d.y);
  s.z = (a.z + b.z) + (c.z + d.z);
  s.w = (a.w + b.w) + (c.w + d.w);
  ((float4*)out)[i] = s;
}

// ---------------- dtproj: fp32 VALU GEMM K=48, both dirs ------------------
__global__ __launch_bounds__(256) void dtproj(
    const float* __restrict__ dblB,    // [2][4096][80]
    const float* __restrict__ w_f, const float* __restrict__ w_r,
    const float* __restrict__ b_f, const float* __restrict__ b_r,
    float* __restrict__ dtOut)         // [2][4096][1536]
{
  const int dir = blockIdx.z;
  const float* A = dblB + (long)dir * (B_SZ * L_SEQ) * 80;
  const float* W = dir ? w_r : w_f;
  const float* bias = dir ? b_r : b_f;
  float* C0 = dtOut + (long)dir * B_SZ * L_SEQ * D_INNER;
  __shared__ float As[16][132];
  __shared__ float Ws[16][132];
  const int tid = threadIdx.x;
  const int m0 = blockIdx.y * 128, n0 = blockIdx.x * 128;
  const int tx = tid & 15, ty = tid >> 4;
  const int lm = tid >> 1;
  const int lk = (tid & 1) * 8;
  const float* Aptr = A + (long)(m0 + lm) * 80 + lk;
  const float* Wptr = W + (long)(n0 + lm) * DT_RANK + lk;
  float acc[8][8] = {};
  for (int k0 = 0; k0 < DT_RANK; k0 += 16) {
    float4 a0 = *(const float4*)(Aptr + k0);
    float4 a1 = *(const float4*)(Aptr + k0 + 4);
    float4 w0 = *(const float4*)(Wptr + k0);
    float4 w1 = *(const float4*)(Wptr + k0 + 4);
    As[lk + 0][lm] = a0.x; As[lk + 1][lm] = a0.y; As[lk + 2][lm] = a0.z; As[lk + 3][lm] = a0.w;
    As[lk + 4][lm] = a1.x; As[lk + 5][lm] = a1.y; As[lk + 6][lm] = a1.z; As[lk + 7][lm] = a1.w;
    Ws[lk + 0][lm] = w0.x; Ws[lk + 1][lm] = w0.y; Ws[lk + 2][lm] = w0.z; Ws[lk + 3][lm] = w0.w;
    Ws[lk + 4][lm] = w1.x; Ws[lk + 5][lm] = w1.y; Ws[lk + 6][lm] = w1.z; Ws[lk + 7][lm] = w1.w;
    __syncthreads();
    #pragma unroll
    for (int kk = 0; kk < 16; ++kk) {
      float4 av0 = *(const float4*)&As[kk][ty * 4];
      float4 av1 = *(const float4*)&As[kk][64 + ty * 4];
      float4 bv0 = *(const float4*)&Ws[kk][tx * 4];
      float4 bv1 = *(const float4*)&Ws[kk][64 + tx * 4];
      float am[8] = {av0.x, av0.y, av0.z, av0.w, av1.x, av1.y, av1.z, av1.w};
      float bn[8] = {bv0.x, bv0.y, bv0.z, bv0.w, bv1.x, bv1.y, bv1.z, bv1.w};
      #pragma unroll
      for (int i = 0; i < 8; ++i)
        #pragma unroll
        for (int j = 0; j < 8; ++j) acc[i][j] = fmaf(am[i], bn[j], acc[i][j]);
    }
    __syncthreads();
  }
  #pragma unroll
  for (int i = 0; i < 8; ++i) {
    int row = m0 + ty * 4 + (i & 3) + ((i >> 2) << 6);
    #pragma unroll
    for (int j = 0; j < 8; ++j) {
      int n = n0 + tx * 4 + (j & 3) + ((j >> 2) << 6);
      float v = acc[i][j] + bias[n];
      C0[(long)row * D_INNER + n] = softplusf(v);
    }
  }
}

// ---------------- xproj: split-K tall-skinny GEMM (N=80) ------------------
__global__ __launch_bounds__(256) void xproj_splitk(
    const float* __restrict__ X,
    const float* __restrict__ xproj_f, const float* __restrict__ xproj_r,
    float* __restrict__ partial)
{
  const int tid = threadIdx.x;
  const int m0 = blockIdx.x * 64;
  const int kz = blockIdx.y;
  const int dir = blockIdx.z;
  const float* W = dir ? xproj_r : xproj_f;
  const float* A = X + (long)dir * B_SZ * L_SEQ * D_INNER;
  __shared__ float As[16][65];
  __shared__ float Ws[16][81];
  const int lk = tid & 15, lr = tid >> 4;
  const int tx = tid & 15, ty = tid >> 4;
  float acc[4][5] = {};
  const int kbase = kz * KCH;
  for (int k0 = 0; k0 < KCH; k0 += 16) {
    #pragma unroll
    for (int i = 0; i < 4; ++i)
      As[lk][lr + 16 * i] = A[(long)(m0 + lr + 16 * i) * D_INNER + kbase + k0 + lk];
    for (int r = lr; r < 80; r += 16)
      Ws[lk][r] = W[(long)r * D_INNER + kbase + k0 + lk];
    __syncthreads();
    #pragma unroll
    for (int kk = 0; kk < 16; ++kk) {
      float a[4], b[5];
      #pragma unroll
      for (int i = 0; i < 4; ++i) a[i] = As[kk][ty + 16 * i];
      #pragma unroll
      for (int j = 0; j < 5; ++j) b[j] = Ws[kk][tx * 5 + j];
      #pragma unroll
      for (int i = 0; i < 4; ++i)
        #pragma unroll
        for (int j = 0; j < 5; ++j) acc[i][j] = fmaf(a[i], b[j], acc[i][j]);
    }
    __syncthreads();
  }
  float* P = partial + (((long)dir * NSPL + kz) * (B_SZ * L_SEQ) + m0) * 80;
  #pragma unroll
  for (int i = 0; i < 4; ++i)
    #pragma unroll
    for (int j = 0; j < 5; ++j)
      P[(long)(ty + 16 * i) * 80 + tx * 5 + j] = acc[i][j];
}

__global__ __launch_bounds__(256) void xproj_reduce(
    const float* __restrict__ partial, float* __restrict__ dbl)
{
  long idx = (long)blockIdx.x * 256 + threadIdx.x;
  const long plane = (long)B_SZ * L_SEQ * 80;
  long dir = idx / plane;
  long rc = idx % plane;
  const float* P = partial + dir * NSPL * plane + rc;
  float s = 0.f;
  #pragma unroll
  for (int z = 0; z < NSPL; ++z) s += P[z * plane];
  dbl[idx] = s;
}

// -------- causal depthwise conv (w=4) + bias + silu, float4 ---------------
__global__ __launch_bounds__(256) void conv_silu_v4(
    const float* __restrict__ xpre,
    const float* __restrict__ w_f, const float* __restrict__ b_f,
    const float* __restrict__ w_r, const float* __restrict__ b_r,
    float* __restrict__ xconv)
{
  long i4 = (long)blockIdx.x * 256 + threadIdx.x;
  const long total4 = 2L * B_SZ * L_SEQ * D_INNER / 4;
  if (i4 >= total4) return;
  long idx = i4 * 4;
  int d0 = (int)(idx % D_INNER);
  long r = idx / D_INNER;
  int t = (int)(r & (L_SEQ - 1));
  int dir = (int)(r >> 12);
  const float* w  = dir ? w_r : w_f;
  const float* cb = dir ? b_r : b_f;
  float4 a = *(const float4*)&cb[d0];
  float4 wc[4];
  #pragma unroll
  for (int i = 0; i < 4; ++i) wc[i] = *(const float4*)&w[(d0 + i) * 4];
  #pragma unroll
  for (int k = 0; k < 4; ++k) {
    if (t - 3 + k >= 0) {
      float4 xv = *(const float4*)&xpre[(r - 3 + k) * D_INNER + d0];
      a.x = fmaf(((const float*)&wc[0])[k], xv.x, a.x);
      a.y = fmaf(((const float*)&wc[1])[k], xv.y, a.y);
      a.z = fmaf(((const float*)&wc[2])[k], xv.z, a.z);
      a.w = fmaf(((const float*)&wc[3])[k], xv.w, a.w);
    }
  }
  a.x = siluf(a.x); a.y = siluf(a.y); a.z = siluf(a.z); a.w = siluf(a.w);
  *(float4*)&xconv[idx] = a;
}

// ---------------- chunked selective scan ----------------
__global__ __launch_bounds__(256) void scan_part1(
    const float* __restrict__ dt, const float* __restrict__ x,
    const float* __restrict__ dbl,
    const float* __restrict__ A_log_f, const float* __restrict__ A_log_r,
    float* __restrict__ stateS, float* __restrict__ stateP)
{
  const int tid = threadIdx.x;
  const int chunk = blockIdx.x / NDG;
  const int d = (blockIdx.x % NDG) * 256 + tid;
  const int b = blockIdx.y, dir = blockIdx.z;
  const float* A_log = dir ? A_log_r : A_log_f;
  float Arow[D_STATE];
  #pragma unroll
  for (int n = 0; n < D_STATE; ++n) Arow[n] = -expf(A_log[d * D_STATE + n]);
  float h[D_STATE], P[D_STATE];
  #pragma unroll
  for (int n = 0; n < D_STATE; ++n) { h[n] = 0.f; P[n] = 1.f; }
  const long rowbase = ((long)dir * B_SZ + b) * L_SEQ + (long)chunk * TC;
  __shared__ float bt[TC][D_STATE];
  for (int i = tid; i < TC * D_STATE; i += 256) {
    int t = i >> 4, n = i & 15;
    bt[t][n] = dbl[(rowbase + t) * 80 + 48 + n];
  }
  __syncthreads();
  for (int tj = 0; tj < TC; ++tj) {
    long off = (rowbase + tj) * D_INNER + d;
    float dtv = dt[off];
    float xv = x[off];
    float dtx = dtv * xv;
    #pragma unroll
    for (int n = 0; n < D_STATE; ++n) {
      float dA = __expf(dtv * Arow[n]);
      P[n] *= dA;
      h[n] = fmaf(h[n], dA, dtx * bt[tj][n]);
    }
  }
  long base = ((((long)dir * B_SZ + b) * NC + chunk) * D_INNER + d) * D_STATE;
  #pragma unroll
  for (int n = 0; n < D_STATE; ++n) { stateS[base + n] = h[n]; stateP[base + n] = P[n]; }
}

__global__ __launch_bounds__(256) void scan_fix(
    float* __restrict__ stateS, const float* __restrict__ stateP)
{
  const long idx = (long)blockIdx.x * 256 + threadIdx.x;
  const int DN = D_INNER * D_STATE;
  const long dirb = idx / DN;
  const int dn = (int)(idx % DN);
  long base = dirb * NC * DN + dn;
  float h = 0.f;
  for (int c = 0; c < NC; ++c) {
    long o = base + (long)c * DN;
    float S = stateS[o];
    float Pc = stateP[o];
    stateS[o] = h;
    h = fmaf(h, Pc, S);
  }
}

__global__ __launch_bounds__(256) void scan_part2(
    const float* __restrict__ dt, float* __restrict__ xy,
    const float* __restrict__ dbl, const float* __restrict__ z,
    const float* __restrict__ A_log_f, const float* __restrict__ A_log_r,
    const float* __restrict__ Ds_f, const float* __restrict__ Ds_r,
    const float* __restrict__ stateS)
{
  const int tid = threadIdx.x;
  const int chunk = blockIdx.x / NDG;
  const int d = (blockIdx.x % NDG) * 256 + tid;
  const int b = blockIdx.y, dir = blockIdx.z;
  const float* A_log = dir ? A_log_r : A_log_f;
  const float* Ds = dir ? Ds_r : Ds_f;
  float Arow[D_STATE];
  #pragma unroll
  for (int n = 0; n < D_STATE; ++n) Arow[n] = -expf(A_log[d * D_STATE + n]);
  const float Dd = Ds[d];
  float h[D_STATE];
  long sbase = ((((long)dir * B_SZ + b) * NC + chunk) * D_INNER + d) * D_STATE;
  #pragma unroll
  for (int n = 0; n < D_STATE; ++n) h[n] = stateS[sbase + n];
  const long rowbase = ((long)dir * B_SZ + b) * L_SEQ + (long)chunk * TC;
  __shared__ float bc[TC][2 * D_STATE];
  for (int i = tid; i < TC * 2 * D_STATE; i += 256) {
    int t = i >> 5, n = i & 31;
    bc[t][n] = dbl[(rowbase + t) * 80 + 48 + n];
  }
  __syncthreads();
  for (int tj = 0; tj < TC; ++tj) {
    long off = (rowbase + tj) * D_INNER + d;
    float dtv = dt[off];
    float xv = xy[off];
    float zv = z[off];
    float dtx = dtv * xv;
    float y = 0.f;
    #pragma unroll
    for (int n = 0; n < D_STATE; ++n) {
      float dA = __expf(dtv * Arow[n]);
      h[n] = fmaf(h[n], dA, dtx * bc[tj][n]);
      y = fmaf(h[n], bc[tj][16 + n], y);
    }
    y = fmaf(xv, Dd, y);
    y *= siluf(zv);
    xy[off] = y;
  }
}

extern "C" void kernel_launch(void* const* d_in, const int* in_sizes, int n_in,
                              void* d_out, int out_size, void* d_ws, size_t ws_size,
                              hipStream_t stream) {
  const float* h        = (const float*)d_in[0];
  const float* in_proj[2] = {(const float*)d_in[1], (const float*)d_in[10]};
  const float* conv_w[2]  = {(const float*)d_in[2], (const float*)d_in[11]};
  const float* conv_b[2]  = {(const float*)d_in[3], (const float*)d_in[12]};
  const float* xproj[2]   = {(const float*)d_in[4], (const float*)d_in[13]};
  const float* dtw[2]     = {(const float*)d_in[5], (const float*)d_in[14]};
  const float* dtb[2]     = {(const float*)d_in[6], (const float*)d_in[15]};
  const float* A_log[2]   = {(const float*)d_in[7], (const float*)d_in[16]};
  const float* Dsk[2]     = {(const float*)d_in[8], (const float*)d_in[17]};
  const float* outp[2]    = {(const float*)d_in[9], (const float*)d_in[18]};
  float* out = (float*)d_out;
  float* ws = (float*)d_ws;

  const long S1 = (long)B_SZ * L_SEQ * D_INNER;   // 6,291,456
  const int M = B_SZ * L_SEQ;                     // 4096
  float* xpre  = ws;                 // [2][4096][1536] (x-preconv -> dt -> outproj partial)
  float* zbuf  = ws + 2 * S1;
  float* xconv = ws + 4 * S1;        // x, then y in-place
  float* dbl   = ws + 6 * S1;        // [2][4096][80]
  float* base4 = dbl + 2L * M * 80;

  // bf16 hi/lo planes (phase A); scan states / xproj partials overlay later
  unsigned short* hh  = (unsigned short*)base4;             // 3,145,728 each
  unsigned short* hl  = hh + 3145728;
  unsigned short* w0h = hl + 3145728;                       // 2,359,296 each
  unsigned short* w0l = w0h + 2359296;
  unsigned short* w1h = w0l + 2359296;
  unsigned short* w1l = w1h + 2359296;
  unsigned short* o0h = w1l + 2359296;                      // 1,179,648 each (live till end)
  unsigned short* o0l = o0h + 1179648;
  unsigned short* o1h = o0l + 1179648;
  unsigned short* o1l = o1h + 1179648;
  float* xpartial = base4;           // xproj partials (2.62M fl) overlay hh/hl after in_proj
  float* stS = base4;                // 3.15M fl (overlays hh/hl, dead after in_proj)
  float* stP = stS + 3145728;        // 3.15M fl (overlays w-planes, dead after in_proj)
  float* opartial = xpre;            // [4][4096][768] = 12.58M fl (xpre dead after scan_part2)

  dim3 blk(256);

  // 0. pre-convert h + all GEMM weights to bf16 hi/lo planes (one dispatch)
  cvt_all<<<dim3(9984), blk, 0, stream>>>(
      h, hh, hl, in_proj[0], w0h, w0l, in_proj[1], w1h, w1l,
      outp[0], o0h, o0l, outp[1], o1h, o1l);

  // 1. in_proj (both dirs) -> x (pre-conv) and z
  gemm_inproj<<<dim3(1536), blk, 0, stream>>>(hh, hl, w0h, w0l, w1h, w1l, xpre, zbuf);

  // 2. conv + silu
  conv_silu_v4<<<dim3((unsigned)(2 * S1 / 4 / 256)), blk, 0, stream>>>(
      xpre, conv_w[0], conv_b[0], conv_w[1], conv_b[1], xconv);

  // 3. xproj (split-K) -> dbl
  {
    dim3 grid(M / 64, NSPL, 2);
    xproj_splitk<<<grid, blk, 0, stream>>>(xconv, xproj[0], xproj[1], xpartial);
    long n = 2L * M * 80;
    xproj_reduce<<<dim3((unsigned)(n / 256)), blk, 0, stream>>>(xpartial, dbl);
  }
  // 4. dtproj + bias + softplus -> dt (overwrites xpre), both dirs
  {
    dim3 grid(D_INNER / 128, M / 128, 2);
    dtproj<<<grid, blk, 0, stream>>>(dbl, dtw[0], dtw[1], dtb[0], dtb[1], xpre);
  }
  // 5. chunked scan (y in place of xconv)
  {
    dim3 grid1(NC * NDG, B_SZ, 2);
    scan_part1<<<grid1, blk, 0, stream>>>(xpre, xconv, dbl,
        A_log[0], A_log[1], stS, stP);
    long nfix = 2L * B_SZ * D_INNER * D_STATE;
    scan_fix<<<dim3((unsigned)(nfix / 256)), blk, 0, stream>>>(stS, stP);
    scan_part2<<<grid1, blk, 0, stream>>>(xpre, xconv, dbl, zbuf,
        A_log[0], A_log[1], Dsk[0], Dsk[1], stS);
  }
  // 6. out_proj: split-(dir,K) partials + reduce
  gemm_outproj_sk<<<dim3(768), blk, 0, stream>>>(xconv, o0h, o0l, o1h, o1l, opartial);
  outproj_reduce<<<dim3((unsigned)(M * (long)D_MODEL / 4 / 256)), blk, 0, stream>>>(opartial, out);
}